// Round 1
// baseline (2658.743 us; speedup 1.0000x reference)
//
#include <hip/hip_runtime.h>
#include <hip/hip_bf16.h>

#define N_TOK 2048
#define HID   2048
#define NH    32
#define NKV   8
#define HD    64
#define NEXP  4
#define CHUNK (N_TOK / NEXP)   // 512
#define KV_DIM (NKV * HD)      // 512

// ---------------------------------------------------------------------------
// fp32 GEMM, 64x64 output tile, BK=16, 256 threads, optional row routing.
// routed: row r = sort_idx[i] uses expert i/CHUNK; reads X[r], writes OUT[r].
// ---------------------------------------------------------------------------
__global__ __launch_bounds__(256)
void gemm_tile64(const float* __restrict__ X, const float* __restrict__ W,
                 const int* __restrict__ sidx, float* __restrict__ OUT,
                 int dout, int routed)
{
    __shared__ float As[16][65];   // [k][m], +1 pad breaks stride conflicts
    __shared__ float Bs[16][65];   // [k][n]
    __shared__ int   ridx[64];

    const int t  = threadIdx.x;
    const int i0 = blockIdx.y * 64;   // sorted-position tile base
    const int n0 = blockIdx.x * 64;

    if (t < 64) ridx[t] = routed ? sidx[i0 + t] : (i0 + t);
    __syncthreads();

    const float* Wb = W + (routed ? (size_t)(i0 / CHUNK) * HID * (size_t)dout : 0);

    const int am  = t >> 2;          // 0..63  A-tile row
    const int ak4 = (t & 3) << 2;    // 0,4,8,12
    const int bk  = t >> 4;          // 0..15  B-tile k row
    const int bn4 = (t & 15) << 2;   // 0..60

    const float* xrow = X  + (size_t)ridx[am] * HID;
    const float* wrow = Wb + (size_t)bk * dout + n0 + bn4;

    float acc[4][4];
#pragma unroll
    for (int i = 0; i < 4; i++)
#pragma unroll
        for (int j = 0; j < 4; j++) acc[i][j] = 0.f;

    const int tm = t >> 4, tn = t & 15;

    for (int k0 = 0; k0 < HID; k0 += 16) {
        float4 av = *(const float4*)(xrow + k0 + ak4);
        float4 bv = *(const float4*)(wrow + (size_t)k0 * dout);
        As[ak4 + 0][am] = av.x;
        As[ak4 + 1][am] = av.y;
        As[ak4 + 2][am] = av.z;
        As[ak4 + 3][am] = av.w;
        Bs[bk][bn4 + 0] = bv.x;   // scalar stores: 65-pad keeps these ~2-way
        Bs[bk][bn4 + 1] = bv.y;
        Bs[bk][bn4 + 2] = bv.z;
        Bs[bk][bn4 + 3] = bv.w;
        __syncthreads();
#pragma unroll
        for (int kk = 0; kk < 16; kk++) {
            float a[4], b[4];
#pragma unroll
            for (int i = 0; i < 4; i++) a[i] = As[kk][tm * 4 + i];
#pragma unroll
            for (int j = 0; j < 4; j++) b[j] = Bs[kk][tn * 4 + j];
#pragma unroll
            for (int i = 0; i < 4; i++)
#pragma unroll
                for (int j = 0; j < 4; j++) acc[i][j] += a[i] * b[j];
        }
        __syncthreads();
    }

#pragma unroll
    for (int i = 0; i < 4; i++) {
        int r = ridx[tm * 4 + i];
        float4 o4 = make_float4(acc[i][0], acc[i][1], acc[i][2], acc[i][3]);
        *(float4*)(OUT + (size_t)r * dout + n0 + tn * 4) = o4;
    }
}

// ---------------------------------------------------------------------------
// Per-(row, head) RMSNorm over HD=64 + NeoX RoPE. One wave (64 lanes) / head.
// ---------------------------------------------------------------------------
__global__ __launch_bounds__(64)
void norm_rope(float* __restrict__ buf, const float* __restrict__ w,
               const int* __restrict__ positions, int nheads)
{
    const int row  = blockIdx.x;
    const int head = blockIdx.y;
    const int lane = threadIdx.x;           // = d index, 0..63
    const int stride = nheads * HD;

    float* p = buf + (size_t)row * stride + head * HD + lane;
    float x = *p;

    float ss = x * x;
#pragma unroll
    for (int off = 32; off > 0; off >>= 1) ss += __shfl_xor(ss, off, 64);
    float rs = rsqrtf(ss * (1.0f / HD) + 1e-6f);
    float xn = x * rs * w[lane];

    int   j  = lane & 31;                                   // freq index
    float inv_freq = powf(10000.0f, -(float)j * (1.0f / 32.0f));
    float fr = (float)positions[row] * inv_freq;
    float c = cosf(fr), s = sinf(fr);

    float partner = __shfl_xor(xn, 32, 64);                 // x[d ^ 32]
    // lane<32: x1=xn, x2=partner -> x1*c - x2*s
    // lane>=32: x2=xn, x1=partner -> x2*c + x1*s
    float out = (lane < 32) ? (xn * c - partner * s) : (xn * c + partner * s);
    *p = out;
}

// ---------------------------------------------------------------------------
// Flash-style causal GQA attention, fp32.
// Block = 256 threads = (row 0..63) x (quad 0..3). Q-tile 64 rows, K-tile 32.
// Thread (row, quad) owns O[row][quad*16 .. +16] and S[row][quad*8 .. +8].
// ---------------------------------------------------------------------------
__global__ __launch_bounds__(256)
void attn_kernel(const float* __restrict__ q, const float* __restrict__ k,
                 const float* __restrict__ v, const int* __restrict__ positions,
                 float* __restrict__ o)
{
    __shared__ float Qs[64][65];
    __shared__ float Ks[32][65];
    __shared__ float Vs[32][65];
    __shared__ float Ss[64][33];
    __shared__ float mrow[64], lrow[64], arow[64];

    const int qt   = blockIdx.x;
    const int head = blockIdx.y;
    const int kvh  = head >> 2;           // NH/NKV = 4
    const int q0   = qt * 64;
    const int t    = threadIdx.x;
    const int row  = t & 63;
    const int quad = t >> 6;
    const int dbase = quad * 16;
    const float scale = 0.125f;           // HD^-0.5

    for (int idx = t; idx < 64 * 64; idx += 256) {
        int r = idx >> 6, d = idx & 63;
        Qs[r][d] = q[(size_t)(q0 + r) * HID + head * HD + d] * scale;
    }
    if (t < 64) { mrow[t] = -1e30f; lrow[t] = 0.f; }

    float oacc[16];
#pragma unroll
    for (int i = 0; i < 16; i++) oacc[i] = 0.f;

    const int pq_r = positions[q0 + row];
    const int nkt  = 2 * qt + 2;          // k tiles of 32 covering k <= q0+63

    for (int kt = 0; kt < nkt; kt++) {
        const int k0 = kt * 32;
        __syncthreads();                  // Ks/Vs/Ss free; Qs/mrow ready (kt=0)
        for (int idx = t; idx < 32 * 64; idx += 256) {
            int r = idx >> 6, d = idx & 63;
            Ks[r][d] = k[(size_t)(k0 + r) * KV_DIM + kvh * HD + d];
            Vs[r][d] = v[(size_t)(k0 + r) * KV_DIM + kvh * HD + d];
        }
        __syncthreads();

        const bool need_mask = (k0 + 31) >= q0;
#pragma unroll
        for (int j = 0; j < 8; j++) {
            int c = quad * 8 + j;
            float s = 0.f;
#pragma unroll
            for (int d = 0; d < 64; d++) s += Qs[row][d] * Ks[c][d];
            if (need_mask && positions[k0 + c] > pq_r) s = -1e30f;
            Ss[row][c] = s;
        }
        __syncthreads();

        if (t < 64) {                     // wave 0: per-row online softmax
            float m_old = mrow[t];
            float mt = m_old;
            for (int c = 0; c < 32; c++) mt = fmaxf(mt, Ss[t][c]);
            float alpha = __expf(m_old - mt);
            float lsum = 0.f;
            for (int c = 0; c < 32; c++) {
                float pcv = __expf(Ss[t][c] - mt);
                Ss[t][c] = pcv;
                lsum += pcv;
            }
            mrow[t] = mt;
            lrow[t] = lrow[t] * alpha + lsum;
            arow[t] = alpha;
        }
        __syncthreads();

        float alpha = arow[row];
#pragma unroll
        for (int i = 0; i < 16; i++) oacc[i] *= alpha;
        for (int c = 0; c < 32; c++) {
            float pcv = Ss[row][c];
#pragma unroll
            for (int i = 0; i < 16; i++) oacc[i] += pcv * Vs[c][dbase + i];
        }
    }

    float linv = 1.f / lrow[row];
#pragma unroll
    for (int i = 0; i < 16; i++)
        o[(size_t)(q0 + row) * HID + head * HD + dbase + i] = oacc[i] * linv;
}

// ---------------------------------------------------------------------------
extern "C" void kernel_launch(void* const* d_in, const int* in_sizes, int n_in,
                              void* d_out, int out_size, void* d_ws, size_t ws_size,
                              hipStream_t stream)
{
    (void)in_sizes; (void)n_in; (void)out_size; (void)ws_size;

    const float* hidden    = (const float*)d_in[0];
    const int*   positions = (const int*)  d_in[1];
    const int*   sort_idx  = (const int*)  d_in[2];
    const float* q_proj_w  = (const float*)d_in[3];
    const float* o_proj_w  = (const float*)d_in[4];
    const float* k_w       = (const float*)d_in[5];
    const float* v_w       = (const float*)d_in[6];
    const float* q_norm_w  = (const float*)d_in[7];
    const float* k_norm_w  = (const float*)d_in[8];
    float* out = (float*)d_out;

    // workspace: q (N*2048) | k (N*512) | v (N*512) | o (N*2048) = 40 MB fp32
    float* qbuf = (float*)d_ws;
    float* kbuf = qbuf + (size_t)N_TOK * HID;
    float* vbuf = kbuf + (size_t)N_TOK * KV_DIM;
    float* obuf = vbuf + (size_t)N_TOK * KV_DIM;

    gemm_tile64<<<dim3(HID / 64,   N_TOK / 64), 256, 0, stream>>>(hidden, q_proj_w, sort_idx, qbuf, HID, 1);
    gemm_tile64<<<dim3(KV_DIM / 64, N_TOK / 64), 256, 0, stream>>>(hidden, k_w, nullptr, kbuf, KV_DIM, 0);
    gemm_tile64<<<dim3(KV_DIM / 64, N_TOK / 64), 256, 0, stream>>>(hidden, v_w, nullptr, vbuf, KV_DIM, 0);

    norm_rope<<<dim3(N_TOK, NH),  64, 0, stream>>>(qbuf, q_norm_w, positions, NH);
    norm_rope<<<dim3(N_TOK, NKV), 64, 0, stream>>>(kbuf, k_norm_w, positions, NKV);

    attn_kernel<<<dim3(N_TOK / 64, NH), 256, 0, stream>>>(qbuf, kbuf, vbuf, positions, obuf);

    gemm_tile64<<<dim3(HID / 64, N_TOK / 64), 256, 0, stream>>>(obuf, o_proj_w, sort_idx, out, HID, 1);
}

// Round 2
// 1399.332 us; speedup vs baseline: 1.9000x; 1.9000x over previous
//
#include <hip/hip_runtime.h>
#include <hip/hip_bf16.h>

#define N_TOK 2048
#define HID   2048
#define NH    32
#define NKV   8
#define HD    64
#define NEXP  4
#define CHUNK (N_TOK / NEXP)   // 512
#define KV_DIM (NKV * HD)      // 512

typedef __attribute__((ext_vector_type(8))) short short8;
typedef __attribute__((ext_vector_type(4))) float float4v;

__device__ inline short f2bf(float f) {
    __hip_bfloat16 h = __float2bfloat16(f);
    return *reinterpret_cast<short*>(&h);
}

// ---------------------------------------------------------------------------
// fp32 GEMM, 64x64 output tile, BK=16, 256 threads, optional row routing.
// ---------------------------------------------------------------------------
__global__ __launch_bounds__(256)
void gemm_tile64(const float* __restrict__ X, const float* __restrict__ W,
                 const int* __restrict__ sidx, float* __restrict__ OUT,
                 int dout, int routed)
{
    __shared__ float As[16][65];
    __shared__ float Bs[16][65];
    __shared__ int   ridx[64];

    const int t  = threadIdx.x;
    const int i0 = blockIdx.y * 64;
    const int n0 = blockIdx.x * 64;

    if (t < 64) ridx[t] = routed ? sidx[i0 + t] : (i0 + t);
    __syncthreads();

    const float* Wb = W + (routed ? (size_t)(i0 / CHUNK) * HID * (size_t)dout : 0);

    const int am  = t >> 2;
    const int ak4 = (t & 3) << 2;
    const int bk  = t >> 4;
    const int bn4 = (t & 15) << 2;

    const float* xrow = X  + (size_t)ridx[am] * HID;
    const float* wrow = Wb + (size_t)bk * dout + n0 + bn4;

    float acc[4][4];
#pragma unroll
    for (int i = 0; i < 4; i++)
#pragma unroll
        for (int j = 0; j < 4; j++) acc[i][j] = 0.f;

    const int tm = t >> 4, tn = t & 15;

    for (int k0 = 0; k0 < HID; k0 += 16) {
        float4 av = *(const float4*)(xrow + k0 + ak4);
        float4 bv = *(const float4*)(wrow + (size_t)k0 * dout);
        As[ak4 + 0][am] = av.x;
        As[ak4 + 1][am] = av.y;
        As[ak4 + 2][am] = av.z;
        As[ak4 + 3][am] = av.w;
        Bs[bk][bn4 + 0] = bv.x;
        Bs[bk][bn4 + 1] = bv.y;
        Bs[bk][bn4 + 2] = bv.z;
        Bs[bk][bn4 + 3] = bv.w;
        __syncthreads();
#pragma unroll
        for (int kk = 0; kk < 16; kk++) {
            float a[4], b[4];
#pragma unroll
            for (int i = 0; i < 4; i++) a[i] = As[kk][tm * 4 + i];
#pragma unroll
            for (int j = 0; j < 4; j++) b[j] = Bs[kk][tn * 4 + j];
#pragma unroll
            for (int i = 0; i < 4; i++)
#pragma unroll
                for (int j = 0; j < 4; j++) acc[i][j] += a[i] * b[j];
        }
        __syncthreads();
    }

#pragma unroll
    for (int i = 0; i < 4; i++) {
        int r = ridx[tm * 4 + i];
        float4 o4 = make_float4(acc[i][0], acc[i][1], acc[i][2], acc[i][3]);
        *(float4*)(OUT + (size_t)r * dout + n0 + tn * 4) = o4;
    }
}

// ---------------------------------------------------------------------------
// Per-(row, head) RMSNorm + NeoX RoPE. One wave / head.
// ---------------------------------------------------------------------------
__global__ __launch_bounds__(64)
void norm_rope(float* __restrict__ buf, const float* __restrict__ w,
               const int* __restrict__ positions, int nheads)
{
    const int row  = blockIdx.x;
    const int head = blockIdx.y;
    const int lane = threadIdx.x;
    const int stride = nheads * HD;

    float* p = buf + (size_t)row * stride + head * HD + lane;
    float x = *p;

    float ss = x * x;
#pragma unroll
    for (int off = 32; off > 0; off >>= 1) ss += __shfl_xor(ss, off, 64);
    float rs = rsqrtf(ss * (1.0f / HD) + 1e-6f);
    float xn = x * rs * w[lane];

    int   j  = lane & 31;
    float inv_freq = powf(10000.0f, -(float)j * (1.0f / 32.0f));
    float fr = (float)positions[row] * inv_freq;
    float c = cosf(fr), s = sinf(fr);

    float partner = __shfl_xor(xn, 32, 64);
    float out = (lane < 32) ? (xn * c - partner * s) : (xn * c + partner * s);
    *p = out;
}

// ---------------------------------------------------------------------------
// MFMA flash attention, bf16 compute / fp32 accumulate.
// Block = 4 waves, 1 head, 64 q-rows (wave w owns rows q0+16w..+15).
// K-tile = 32 kv rows. QK^T: 4x mfma_f32_16x16x32_bf16; PV: 4x (K=32 exact).
// Layouts (HW-verified per guide §3):
//   A: A[m=lane&15][k=(lane>>4)*8+j]   B: B[k=(lane>>4)*8+j][n=lane&15]
//   C: col=lane&15, row=(lane>>4)*4+reg
// P goes C-layout -> LDS -> A-layout (m120 pattern).
// ---------------------------------------------------------------------------
__global__ __launch_bounds__(256)
void attn_mfma(const float* __restrict__ q, const float* __restrict__ k,
               const float* __restrict__ v, const int* __restrict__ positions,
               float* __restrict__ o)
{
    // pads: +8 bf16 keeps 16B alignment for ds_read_b128, 2-way banks (free)
    __shared__ __align__(16) short Ks[32][72];       // [krow][d]
    __shared__ __align__(16) short Vt[64][40];       // [d][krow]  (transposed)
    __shared__ __align__(16) short Ps[4][16][40];    // per-wave P tile [m][kcol]

    const int qt   = blockIdx.x;
    const int head = blockIdx.y;
    const int kvh  = head >> 2;
    const int q0   = qt * 64;
    const int t    = threadIdx.x;
    const int lane = t & 63;
    const int wave = t >> 6;
    const int rowg = lane >> 4;        // 0..3
    const int col  = lane & 15;        // 0..15
    const int m0   = q0 + wave * 16;   // wave's q-row base

    // --- Q fragments (A-layout), scale folded in ---
    short8 aq0, aq1;
    {
        const float* qrow = q + (size_t)(m0 + col) * HID + head * HD;
#pragma unroll
        for (int j = 0; j < 8; j++) {
            aq0[j] = f2bf(qrow[rowg * 8 + j] * 0.125f);
            aq1[j] = f2bf(qrow[32 + rowg * 8 + j] * 0.125f);
        }
    }

    float m_i[4], l_i[4];
    int   pq[4];
#pragma unroll
    for (int r = 0; r < 4; r++) {
        m_i[r] = -3e38f; l_i[r] = 0.f;
        pq[r] = positions[m0 + rowg * 4 + r];
    }
    float4v oacc[4];
#pragma unroll
    for (int n = 0; n < 4; n++) oacc[n] = (float4v){0.f, 0.f, 0.f, 0.f};

    const int krow = t >> 3;           // staging: 0..31
    const int d0   = (t & 7) * 8;      // staging: 0,8,..,56
    const int nkt  = 2 * qt + 2;

    for (int kt = 0; kt < nkt; kt++) {
        const int k0 = kt * 32;
        __syncthreads();   // previous tile's PV reads of Ks/Vt done

        // --- stage K (row-major) and V (transposed) as bf16 ---
        {
            const float* kp = k + (size_t)(k0 + krow) * KV_DIM + kvh * HD + d0;
            const float* vp = v + (size_t)(k0 + krow) * KV_DIM + kvh * HD + d0;
            float4 k4a = *(const float4*)(kp);
            float4 k4b = *(const float4*)(kp + 4);
            float4 v4a = *(const float4*)(vp);
            float4 v4b = *(const float4*)(vp + 4);
            short8 kk;
            kk[0] = f2bf(k4a.x); kk[1] = f2bf(k4a.y); kk[2] = f2bf(k4a.z); kk[3] = f2bf(k4a.w);
            kk[4] = f2bf(k4b.x); kk[5] = f2bf(k4b.y); kk[6] = f2bf(k4b.z); kk[7] = f2bf(k4b.w);
            *(short8*)&Ks[krow][d0] = kk;
            Vt[d0 + 0][krow] = f2bf(v4a.x);
            Vt[d0 + 1][krow] = f2bf(v4a.y);
            Vt[d0 + 2][krow] = f2bf(v4a.z);
            Vt[d0 + 3][krow] = f2bf(v4a.w);
            Vt[d0 + 4][krow] = f2bf(v4b.x);
            Vt[d0 + 5][krow] = f2bf(v4b.y);
            Vt[d0 + 6][krow] = f2bf(v4b.z);
            Vt[d0 + 7][krow] = f2bf(v4b.w);
        }
        __syncthreads();

        const bool active = (k0 <= m0 + 15);   // any unmasked col for this wave?
        float alpha[4];

        if (active) {
            // --- QK^T: S[16 rows][32 cols] as two 16x16 C-frags ---
            short8 bk00 = *(const short8*)&Ks[col][rowg * 8];
            short8 bk01 = *(const short8*)&Ks[col][32 + rowg * 8];
            short8 bk10 = *(const short8*)&Ks[16 + col][rowg * 8];
            short8 bk11 = *(const short8*)&Ks[16 + col][32 + rowg * 8];
            float4v c0 = (float4v){0.f, 0.f, 0.f, 0.f};
            float4v c1 = (float4v){0.f, 0.f, 0.f, 0.f};
            c0 = __builtin_amdgcn_mfma_f32_16x16x32_bf16(aq0, bk00, c0, 0, 0, 0);
            c0 = __builtin_amdgcn_mfma_f32_16x16x32_bf16(aq1, bk01, c0, 0, 0, 0);
            c1 = __builtin_amdgcn_mfma_f32_16x16x32_bf16(aq0, bk10, c1, 0, 0, 0);
            c1 = __builtin_amdgcn_mfma_f32_16x16x32_bf16(aq1, bk11, c1, 0, 0, 0);

            // --- online softmax (per-row over the 16-lane col group) ---
            const int pk0 = positions[k0 + col];
            const int pk1 = positions[k0 + 16 + col];
            float s0[4], s1[4], mt[4], psum[4];
#pragma unroll
            for (int r = 0; r < 4; r++) {
                s0[r] = (pq[r] >= pk0) ? c0[r] : -3e38f;
                s1[r] = (pq[r] >= pk1) ? c1[r] : -3e38f;
                mt[r] = fmaxf(s0[r], s1[r]);
            }
#pragma unroll
            for (int off = 1; off < 16; off <<= 1)
#pragma unroll
                for (int r = 0; r < 4; r++)
                    mt[r] = fmaxf(mt[r], __shfl_xor(mt[r], off, 64));
#pragma unroll
            for (int r = 0; r < 4; r++) {
                mt[r] = fmaxf(mt[r], m_i[r]);
                alpha[r] = __expf(m_i[r] - mt[r]);
                m_i[r] = mt[r];
                float p0 = __expf(s0[r] - mt[r]);
                float p1 = __expf(s1[r] - mt[r]);
                Ps[wave][rowg * 4 + r][col]      = f2bf(p0);
                Ps[wave][rowg * 4 + r][16 + col] = f2bf(p1);
                psum[r] = p0 + p1;
            }
#pragma unroll
            for (int off = 1; off < 16; off <<= 1)
#pragma unroll
                for (int r = 0; r < 4; r++)
                    psum[r] += __shfl_xor(psum[r], off, 64);
#pragma unroll
            for (int r = 0; r < 4; r++)
                l_i[r] = l_i[r] * alpha[r] + psum[r];
        }

        __syncthreads();   // Ps visible (and ordered) for A-layout readback

        if (active) {
            // --- PV: O += P(16x32) @ V(32x64), K=32 exact ---
            short8 ap = *(const short8*)&Ps[wave][col][rowg * 8];
#pragma unroll
            for (int n = 0; n < 4; n++) {
                short8 bv = *(const short8*)&Vt[n * 16 + col][rowg * 8];
                float4v acc = oacc[n];
#pragma unroll
                for (int r = 0; r < 4; r++) acc[r] *= alpha[r];
                acc = __builtin_amdgcn_mfma_f32_16x16x32_bf16(ap, bv, acc, 0, 0, 0);
                oacc[n] = acc;
            }
        }
    }

    float linv[4];
#pragma unroll
    for (int r = 0; r < 4; r++) linv[r] = 1.f / l_i[r];
#pragma unroll
    for (int n = 0; n < 4; n++)
#pragma unroll
        for (int r = 0; r < 4; r++)
            o[(size_t)(m0 + rowg * 4 + r) * HID + head * HD + n * 16 + col] =
                oacc[n][r] * linv[r];
}

// ---------------------------------------------------------------------------
extern "C" void kernel_launch(void* const* d_in, const int* in_sizes, int n_in,
                              void* d_out, int out_size, void* d_ws, size_t ws_size,
                              hipStream_t stream)
{
    (void)in_sizes; (void)n_in; (void)out_size; (void)ws_size;

    const float* hidden    = (const float*)d_in[0];
    const int*   positions = (const int*)  d_in[1];
    const int*   sort_idx  = (const int*)  d_in[2];
    const float* q_proj_w  = (const float*)d_in[3];
    const float* o_proj_w  = (const float*)d_in[4];
    const float* k_w       = (const float*)d_in[5];
    const float* v_w       = (const float*)d_in[6];
    const float* q_norm_w  = (const float*)d_in[7];
    const float* k_norm_w  = (const float*)d_in[8];
    float* out = (float*)d_out;

    float* qbuf = (float*)d_ws;
    float* kbuf = qbuf + (size_t)N_TOK * HID;
    float* vbuf = kbuf + (size_t)N_TOK * KV_DIM;
    float* obuf = vbuf + (size_t)N_TOK * KV_DIM;

    gemm_tile64<<<dim3(HID / 64,   N_TOK / 64), 256, 0, stream>>>(hidden, q_proj_w, sort_idx, qbuf, HID, 1);
    gemm_tile64<<<dim3(KV_DIM / 64, N_TOK / 64), 256, 0, stream>>>(hidden, k_w, nullptr, kbuf, KV_DIM, 0);
    gemm_tile64<<<dim3(KV_DIM / 64, N_TOK / 64), 256, 0, stream>>>(hidden, v_w, nullptr, vbuf, KV_DIM, 0);

    norm_rope<<<dim3(N_TOK, NH),  64, 0, stream>>>(qbuf, q_norm_w, positions, NH);
    norm_rope<<<dim3(N_TOK, NKV), 64, 0, stream>>>(kbuf, k_norm_w, positions, NKV);

    attn_mfma<<<dim3(N_TOK / 64, NH), 256, 0, stream>>>(qbuf, kbuf, vbuf, positions, obuf);

    gemm_tile64<<<dim3(HID / 64, N_TOK / 64), 256, 0, stream>>>(obuf, o_proj_w, sort_idx, out, HID, 1);
}

// Round 3
// 728.700 us; speedup vs baseline: 3.6486x; 1.9203x over previous
//
#include <hip/hip_runtime.h>
#include <hip/hip_bf16.h>

#define N_TOK 2048
#define HID   2048
#define NH    32
#define NKV   8
#define HD    64
#define NEXP  4
#define CHUNK (N_TOK / NEXP)   // 512
#define KV_DIM (NKV * HD)      // 512

typedef __attribute__((ext_vector_type(8))) short short8;
typedef __attribute__((ext_vector_type(4))) float float4v;

__device__ inline short f2bf(float f) {
    __hip_bfloat16 h = __float2bfloat16(f);
    return *reinterpret_cast<short*>(&h);
}

// ---------------------------------------------------------------------------
// No-LDS bf16 MFMA GEMM. One wave per block, 64x64 output tile.
// Exploits LLC residency of X (16 MB) and W (<=64 MB): fragments are loaded
// directly from global fp32 and converted in-register -- no LDS, no barriers,
// no weight transpose. Virtual n-tile mapping n = n0 + 4*col + nt makes both
// B-loads and C-stores float4-coalesced.
// MFMA layouts (HW-verified): A[m=lane&15][k=(lane>>4)*8+j],
// B[k=(lane>>4)*8+j][n=lane&15], C col=lane&15 row=(lane>>4)*4+reg.
// ---------------------------------------------------------------------------
__global__ __launch_bounds__(64, 1)
void gemm_mfma(const float* __restrict__ X, const float* __restrict__ W,
               const int* __restrict__ sidx, float* __restrict__ OUT,
               int dout, int routed)
{
    const int lane = threadIdx.x;
    const int col  = lane & 15;
    const int rowg = lane >> 4;
    const int n0   = blockIdx.x * 64;
    const int m0   = blockIdx.y * 64;

    // B base: expert slice + column n0 + 4*col (nt picks .x/.y/.z/.w)
    const float* Wb = W + (routed ? (size_t)(m0 / CHUNK) * HID * (size_t)dout : 0)
                        + (size_t)(n0 + col * 4);
    // A row pointers (routed gather resolved once), pre-offset by rowg*8
    const float* pA[4];
#pragma unroll
    for (int mt = 0; mt < 4; mt++) {
        int gr = m0 + mt * 16 + col;
        int r  = routed ? sidx[gr] : gr;
        pA[mt] = X + (size_t)r * HID + rowg * 8;
    }
    const int kbase = rowg * 8;

    float4v acc[4][4];
#pragma unroll
    for (int mt = 0; mt < 4; mt++)
#pragma unroll
        for (int nt = 0; nt < 4; nt++) acc[mt][nt] = (float4v){0.f, 0.f, 0.f, 0.f};

    float4 A0[4][2], B0[8], A1[4][2], B1[8];

    auto load = [&](float4 (&A)[4][2], float4 (&B)[8], int k0) {
#pragma unroll
        for (int mt = 0; mt < 4; mt++) {
            A[mt][0] = *(const float4*)(pA[mt] + k0);
            A[mt][1] = *(const float4*)(pA[mt] + k0 + 4);
        }
#pragma unroll
        for (int j = 0; j < 8; j++)
            B[j] = *(const float4*)(Wb + (size_t)(k0 + kbase + j) * dout);
    };

    auto compute = [&](const float4 (&A)[4][2], const float4 (&B)[8]) {
        short8 aq[4], bq[4];
#pragma unroll
        for (int mt = 0; mt < 4; mt++) {
            aq[mt][0] = f2bf(A[mt][0].x); aq[mt][1] = f2bf(A[mt][0].y);
            aq[mt][2] = f2bf(A[mt][0].z); aq[mt][3] = f2bf(A[mt][0].w);
            aq[mt][4] = f2bf(A[mt][1].x); aq[mt][5] = f2bf(A[mt][1].y);
            aq[mt][6] = f2bf(A[mt][1].z); aq[mt][7] = f2bf(A[mt][1].w);
        }
#pragma unroll
        for (int j = 0; j < 8; j++) {
            bq[0][j] = f2bf(B[j].x);
            bq[1][j] = f2bf(B[j].y);
            bq[2][j] = f2bf(B[j].z);
            bq[3][j] = f2bf(B[j].w);
        }
#pragma unroll
        for (int mt = 0; mt < 4; mt++)
#pragma unroll
            for (int nt = 0; nt < 4; nt++)
                acc[mt][nt] = __builtin_amdgcn_mfma_f32_16x16x32_bf16(
                    aq[mt], bq[nt], acc[mt][nt], 0, 0, 0);
    };

    // software pipeline: K=32 per compute step, register double-buffered
    load(A0, B0, 0);
    for (int k0 = 0; k0 < HID; k0 += 64) {
        load(A1, B1, k0 + 32);
        compute(A0, B0);
        if (k0 + 64 < HID) load(A0, B0, k0 + 64);
        compute(A1, B1);
    }

    // C store: float4 across nt (cols n0+4*col .. +3), routed row scatter
#pragma unroll
    for (int mt = 0; mt < 4; mt++) {
        int base = m0 + mt * 16 + rowg * 4;
        int rows[4];
        if (routed) {
            int4 s4 = *(const int4*)&sidx[base];
            rows[0] = s4.x; rows[1] = s4.y; rows[2] = s4.z; rows[3] = s4.w;
        } else {
            rows[0] = base; rows[1] = base + 1; rows[2] = base + 2; rows[3] = base + 3;
        }
#pragma unroll
        for (int r = 0; r < 4; r++) {
            float4 v4 = make_float4(acc[mt][0][r], acc[mt][1][r],
                                    acc[mt][2][r], acc[mt][3][r]);
            *(float4*)(OUT + (size_t)rows[r] * dout + n0 + col * 4) = v4;
        }
    }
}

// ---------------------------------------------------------------------------
// Per-(row, head) RMSNorm + NeoX RoPE. One wave / head.
// ---------------------------------------------------------------------------
__global__ __launch_bounds__(64)
void norm_rope(float* __restrict__ buf, const float* __restrict__ w,
               const int* __restrict__ positions, int nheads)
{
    const int row  = blockIdx.x;
    const int head = blockIdx.y;
    const int lane = threadIdx.x;
    const int stride = nheads * HD;

    float* p = buf + (size_t)row * stride + head * HD + lane;
    float x = *p;

    float ss = x * x;
#pragma unroll
    for (int off = 32; off > 0; off >>= 1) ss += __shfl_xor(ss, off, 64);
    float rs = rsqrtf(ss * (1.0f / HD) + 1e-6f);
    float xn = x * rs * w[lane];

    int   j  = lane & 31;
    float inv_freq = powf(10000.0f, -(float)j * (1.0f / 32.0f));
    float fr = (float)positions[row] * inv_freq;
    float c = cosf(fr), s = sinf(fr);

    float partner = __shfl_xor(xn, 32, 64);
    float out = (lane < 32) ? (xn * c - partner * s) : (xn * c + partner * s);
    *p = out;
}

// ---------------------------------------------------------------------------
// MFMA flash attention, bf16 compute / fp32 accumulate. (unchanged from R1)
// ---------------------------------------------------------------------------
__global__ __launch_bounds__(256)
void attn_mfma(const float* __restrict__ q, const float* __restrict__ k,
               const float* __restrict__ v, const int* __restrict__ positions,
               float* __restrict__ o)
{
    __shared__ __align__(16) short Ks[32][72];
    __shared__ __align__(16) short Vt[64][40];
    __shared__ __align__(16) short Ps[4][16][40];

    const int qt   = blockIdx.x;
    const int head = blockIdx.y;
    const int kvh  = head >> 2;
    const int q0   = qt * 64;
    const int t    = threadIdx.x;
    const int lane = t & 63;
    const int wave = t >> 6;
    const int rowg = lane >> 4;
    const int col  = lane & 15;
    const int m0   = q0 + wave * 16;

    short8 aq0, aq1;
    {
        const float* qrow = q + (size_t)(m0 + col) * HID + head * HD;
#pragma unroll
        for (int j = 0; j < 8; j++) {
            aq0[j] = f2bf(qrow[rowg * 8 + j] * 0.125f);
            aq1[j] = f2bf(qrow[32 + rowg * 8 + j] * 0.125f);
        }
    }

    float m_i[4], l_i[4];
    int   pq[4];
#pragma unroll
    for (int r = 0; r < 4; r++) {
        m_i[r] = -3e38f; l_i[r] = 0.f;
        pq[r] = positions[m0 + rowg * 4 + r];
    }
    float4v oacc[4];
#pragma unroll
    for (int n = 0; n < 4; n++) oacc[n] = (float4v){0.f, 0.f, 0.f, 0.f};

    const int krow = t >> 3;
    const int d0   = (t & 7) * 8;
    const int nkt  = 2 * qt + 2;

    for (int kt = 0; kt < nkt; kt++) {
        const int k0 = kt * 32;
        __syncthreads();

        {
            const float* kp = k + (size_t)(k0 + krow) * KV_DIM + kvh * HD + d0;
            const float* vp = v + (size_t)(k0 + krow) * KV_DIM + kvh * HD + d0;
            float4 k4a = *(const float4*)(kp);
            float4 k4b = *(const float4*)(kp + 4);
            float4 v4a = *(const float4*)(vp);
            float4 v4b = *(const float4*)(vp + 4);
            short8 kk;
            kk[0] = f2bf(k4a.x); kk[1] = f2bf(k4a.y); kk[2] = f2bf(k4a.z); kk[3] = f2bf(k4a.w);
            kk[4] = f2bf(k4b.x); kk[5] = f2bf(k4b.y); kk[6] = f2bf(k4b.z); kk[7] = f2bf(k4b.w);
            *(short8*)&Ks[krow][d0] = kk;
            Vt[d0 + 0][krow] = f2bf(v4a.x);
            Vt[d0 + 1][krow] = f2bf(v4a.y);
            Vt[d0 + 2][krow] = f2bf(v4a.z);
            Vt[d0 + 3][krow] = f2bf(v4a.w);
            Vt[d0 + 4][krow] = f2bf(v4b.x);
            Vt[d0 + 5][krow] = f2bf(v4b.y);
            Vt[d0 + 6][krow] = f2bf(v4b.z);
            Vt[d0 + 7][krow] = f2bf(v4b.w);
        }
        __syncthreads();

        const bool active = (k0 <= m0 + 15);
        float alpha[4];

        if (active) {
            short8 bk00 = *(const short8*)&Ks[col][rowg * 8];
            short8 bk01 = *(const short8*)&Ks[col][32 + rowg * 8];
            short8 bk10 = *(const short8*)&Ks[16 + col][rowg * 8];
            short8 bk11 = *(const short8*)&Ks[16 + col][32 + rowg * 8];
            float4v c0 = (float4v){0.f, 0.f, 0.f, 0.f};
            float4v c1 = (float4v){0.f, 0.f, 0.f, 0.f};
            c0 = __builtin_amdgcn_mfma_f32_16x16x32_bf16(aq0, bk00, c0, 0, 0, 0);
            c0 = __builtin_amdgcn_mfma_f32_16x16x32_bf16(aq1, bk01, c0, 0, 0, 0);
            c1 = __builtin_amdgcn_mfma_f32_16x16x32_bf16(aq0, bk10, c1, 0, 0, 0);
            c1 = __builtin_amdgcn_mfma_f32_16x16x32_bf16(aq1, bk11, c1, 0, 0, 0);

            const int pk0 = positions[k0 + col];
            const int pk1 = positions[k0 + 16 + col];
            float s0[4], s1[4], mt[4], psum[4];
#pragma unroll
            for (int r = 0; r < 4; r++) {
                s0[r] = (pq[r] >= pk0) ? c0[r] : -3e38f;
                s1[r] = (pq[r] >= pk1) ? c1[r] : -3e38f;
                mt[r] = fmaxf(s0[r], s1[r]);
            }
#pragma unroll
            for (int off = 1; off < 16; off <<= 1)
#pragma unroll
                for (int r = 0; r < 4; r++)
                    mt[r] = fmaxf(mt[r], __shfl_xor(mt[r], off, 64));
#pragma unroll
            for (int r = 0; r < 4; r++) {
                mt[r] = fmaxf(mt[r], m_i[r]);
                alpha[r] = __expf(m_i[r] - mt[r]);
                m_i[r] = mt[r];
                float p0 = __expf(s0[r] - mt[r]);
                float p1 = __expf(s1[r] - mt[r]);
                Ps[wave][rowg * 4 + r][col]      = f2bf(p0);
                Ps[wave][rowg * 4 + r][16 + col] = f2bf(p1);
                psum[r] = p0 + p1;
            }
#pragma unroll
            for (int off = 1; off < 16; off <<= 1)
#pragma unroll
                for (int r = 0; r < 4; r++)
                    psum[r] += __shfl_xor(psum[r], off, 64);
#pragma unroll
            for (int r = 0; r < 4; r++)
                l_i[r] = l_i[r] * alpha[r] + psum[r];
        }

        __syncthreads();

        if (active) {
            short8 ap = *(const short8*)&Ps[wave][col][rowg * 8];
#pragma unroll
            for (int n = 0; n < 4; n++) {
                short8 bv = *(const short8*)&Vt[n * 16 + col][rowg * 8];
                float4v acc2 = oacc[n];
#pragma unroll
                for (int r = 0; r < 4; r++) acc2[r] *= alpha[r];
                acc2 = __builtin_amdgcn_mfma_f32_16x16x32_bf16(ap, bv, acc2, 0, 0, 0);
                oacc[n] = acc2;
            }
        }
    }

    float linv[4];
#pragma unroll
    for (int r = 0; r < 4; r++) linv[r] = 1.f / l_i[r];
#pragma unroll
    for (int n = 0; n < 4; n++)
#pragma unroll
        for (int r = 0; r < 4; r++)
            o[(size_t)(m0 + rowg * 4 + r) * HID + head * HD + n * 16 + col] =
                oacc[n][r] * linv[r];
}

// ---------------------------------------------------------------------------
extern "C" void kernel_launch(void* const* d_in, const int* in_sizes, int n_in,
                              void* d_out, int out_size, void* d_ws, size_t ws_size,
                              hipStream_t stream)
{
    (void)in_sizes; (void)n_in; (void)out_size; (void)ws_size;

    const float* hidden    = (const float*)d_in[0];
    const int*   positions = (const int*)  d_in[1];
    const int*   sort_idx  = (const int*)  d_in[2];
    const float* q_proj_w  = (const float*)d_in[3];
    const float* o_proj_w  = (const float*)d_in[4];
    const float* k_w       = (const float*)d_in[5];
    const float* v_w       = (const float*)d_in[6];
    const float* q_norm_w  = (const float*)d_in[7];
    const float* k_norm_w  = (const float*)d_in[8];
    float* out = (float*)d_out;

    float* qbuf = (float*)d_ws;
    float* kbuf = qbuf + (size_t)N_TOK * HID;
    float* vbuf = kbuf + (size_t)N_TOK * KV_DIM;
    float* obuf = vbuf + (size_t)N_TOK * KV_DIM;

    gemm_mfma<<<dim3(HID / 64,   N_TOK / 64), 64, 0, stream>>>(hidden, q_proj_w, sort_idx, qbuf, HID, 1);
    gemm_mfma<<<dim3(KV_DIM / 64, N_TOK / 64), 64, 0, stream>>>(hidden, k_w, nullptr, kbuf, KV_DIM, 0);
    gemm_mfma<<<dim3(KV_DIM / 64, N_TOK / 64), 64, 0, stream>>>(hidden, v_w, nullptr, vbuf, KV_DIM, 0);

    norm_rope<<<dim3(N_TOK, NH),  64, 0, stream>>>(qbuf, q_norm_w, positions, NH);
    norm_rope<<<dim3(N_TOK, NKV), 64, 0, stream>>>(kbuf, k_norm_w, positions, NKV);

    attn_mfma<<<dim3(N_TOK / 64, NH), 256, 0, stream>>>(qbuf, kbuf, vbuf, positions, obuf);

    gemm_mfma<<<dim3(HID / 64, N_TOK / 64), 64, 0, stream>>>(obuf, o_proj_w, sort_idx, out, HID, 1);
}

// Round 4
// 521.459 us; speedup vs baseline: 5.0987x; 1.3974x over previous
//
#include <hip/hip_runtime.h>
#include <hip/hip_bf16.h>

#define N_TOK 2048
#define HID   2048
#define NH    32
#define NKV   8
#define HD    64
#define NEXP  4
#define CHUNK (N_TOK / NEXP)   // 512
#define KV_DIM (NKV * HD)      // 512

typedef __attribute__((ext_vector_type(8))) short short8;
typedef __attribute__((ext_vector_type(4))) float float4v;

__device__ inline short f2bf(float f) {
    __hip_bfloat16 h = __float2bfloat16(f);
    return *reinterpret_cast<short*>(&h);
}
__device__ inline float bf2f(short s) {
    __hip_bfloat16 h = *reinterpret_cast<__hip_bfloat16*>(&s);
    return __bfloat162float(h);
}

// ---------------------------------------------------------------------------
// fp32 -> bf16 convert, 8 elems/thread.
// ---------------------------------------------------------------------------
__global__ __launch_bounds__(256)
void cvt_bf16(const float* __restrict__ in, short* __restrict__ out)
{
    size_t i = (size_t)blockIdx.x * 256 + threadIdx.x;   // one per 8 elems
    float4 a = ((const float4*)in)[i * 2];
    float4 b = ((const float4*)in)[i * 2 + 1];
    short8 s;
    s[0] = f2bf(a.x); s[1] = f2bf(a.y); s[2] = f2bf(a.z); s[3] = f2bf(a.w);
    s[4] = f2bf(b.x); s[5] = f2bf(b.y); s[6] = f2bf(b.z); s[7] = f2bf(b.w);
    ((short8*)out)[i] = s;
}

// ---------------------------------------------------------------------------
// Weight transpose+convert: in fp32 [E][K=2048][Nw] -> out bf16 [E][Nw][2048].
// LDS 64x64 tile, both sides coalesced.
// ---------------------------------------------------------------------------
__global__ __launch_bounds__(256)
void wtrans(const float* __restrict__ in, short* __restrict__ out, int Nw)
{
    __shared__ float T[64][65];
    const int k0 = blockIdx.x * 64, n0 = blockIdx.y * 64;
    const size_t eoff = (size_t)blockIdx.z * 2048 * (size_t)Nw;
    const int t = threadIdx.x;
#pragma unroll
    for (int i = 0; i < 16; i++) {
        int idx = t + i * 256, kl = idx >> 6, nl = idx & 63;
        T[kl][nl] = in[eoff + (size_t)(k0 + kl) * Nw + n0 + nl];
    }
    __syncthreads();
#pragma unroll
    for (int i = 0; i < 16; i++) {
        int idx = t + i * 256, nl = idx >> 6, kl = idx & 63;
        out[eoff + (size_t)(n0 + nl) * 2048 + k0 + kl] = f2bf(T[kl][nl]);
    }
}

// ---------------------------------------------------------------------------
// V transpose (bf16): in [N][ldrow] (v cols pre-offset) -> out [HD*NKV][N].
// ---------------------------------------------------------------------------
__global__ __launch_bounds__(256)
void vtrans(const short* __restrict__ v, short* __restrict__ vt, int ldrow)
{
    __shared__ short T[64][66];
    const int n0 = blockIdx.x * 64, h = blockIdx.y;
    const int t = threadIdx.x;
#pragma unroll
    for (int i = 0; i < 16; i++) {
        int idx = t + i * 256, nl = idx >> 6, dl = idx & 63;
        T[nl][dl] = v[(size_t)(n0 + nl) * ldrow + h * HD + dl];
    }
    __syncthreads();
#pragma unroll
    for (int i = 0; i < 16; i++) {
        int idx = t + i * 256, dl = idx >> 6, nl = idx & 63;
        vt[((size_t)h * HD + dl) * N_TOK + n0 + nl] = T[nl][dl];
    }
}

// ---------------------------------------------------------------------------
// bf16 MFMA GEMM, 128x128 tile, BK=32, 4 waves (2x2 of 64x64), LDS-staged.
// X bf16 [rows][2048] (rows gathered via sidx when routed); Wt bf16 [E][N][2048]
// (k-contiguous). OUT row stride ldo, fp32 or bf16. No conversions in K-loop.
// MFMA layouts (verified R1-R3): A[m=col][k=rowg*8+j], B[k=rowg*8+j][n=col],
// C col=lane&15 row=rowg*4+reg.
// ---------------------------------------------------------------------------
__global__ __launch_bounds__(256)
void gemm_bf16(const short* __restrict__ X, const short* __restrict__ Wt,
               const int* __restrict__ sidx, void* __restrict__ OUT,
               int N, int ldo, int routed, int out_bf16)
{
    __shared__ __align__(16) short As[128 * 32];   // [m][k], 64 B rows
    __shared__ __align__(16) short Bs[128 * 32];   // [n][k]
    __shared__ int ridx[128];

    const int t  = threadIdx.x;
    const int m0 = blockIdx.y * 128;
    const int n0 = blockIdx.x * 128;

    if (t < 128) ridx[t] = routed ? sidx[m0 + t] : (m0 + t);

    const short* Wb = Wt + (routed ? (size_t)(m0 / CHUNK) * (size_t)N * 2048 : 0);

    // staging assignment: seg s = t and t+256; r=s>>2, q4=s&3; LDS addr = s*16B
    const int q4 = t & 3;
    __syncthreads();   // ridx ready
    const short* pa0 = X + (size_t)ridx[t >> 2] * 2048 + q4 * 8;
    const short* pa1 = X + (size_t)ridx[64 + (t >> 2)] * 2048 + q4 * 8;
    const short* pb0 = Wb + (size_t)(n0 + (t >> 2)) * 2048 + q4 * 8;
    const short* pb1 = Wb + (size_t)(n0 + 64 + (t >> 2)) * 2048 + q4 * 8;

    const int lane = t & 63;
    const int wave = t >> 6;
    const int col  = lane & 15;
    const int rowg = lane >> 4;
    const int wm   = (wave >> 1) * 64;
    const int wn   = (wave & 1) * 64;

    // frag LDS offsets (shorts), constant across iters
    int offA[4], offB[4];
#pragma unroll
    for (int i = 0; i < 4; i++) {
        offA[i] = (wm + i * 16 + col) * 32 + rowg * 8;
        offB[i] = (wn + i * 16 + col) * 32 + rowg * 8;
    }

    float4v acc[4][4];
#pragma unroll
    for (int mt = 0; mt < 4; mt++)
#pragma unroll
        for (int nt = 0; nt < 4; nt++) acc[mt][nt] = (float4v){0.f, 0.f, 0.f, 0.f};

    for (int k0 = 0; k0 < 2048; k0 += 32) {
        short8 a0 = *(const short8*)(pa0 + k0);
        short8 a1 = *(const short8*)(pa1 + k0);
        short8 b0 = *(const short8*)(pb0 + k0);
        short8 b1 = *(const short8*)(pb1 + k0);
        __syncthreads();   // previous iter's ds_reads done
        *(short8*)&As[t * 8]          = a0;
        *(short8*)&As[(t + 256) * 8]  = a1;
        *(short8*)&Bs[t * 8]          = b0;
        *(short8*)&Bs[(t + 256) * 8]  = b1;
        __syncthreads();   // tile ready

        short8 af[4], bf[4];
#pragma unroll
        for (int i = 0; i < 4; i++) af[i] = *(const short8*)&As[offA[i]];
#pragma unroll
        for (int i = 0; i < 4; i++) bf[i] = *(const short8*)&Bs[offB[i]];
#pragma unroll
        for (int mt = 0; mt < 4; mt++)
#pragma unroll
            for (int nt = 0; nt < 4; nt++)
                acc[mt][nt] = __builtin_amdgcn_mfma_f32_16x16x32_bf16(
                    af[mt], bf[nt], acc[mt][nt], 0, 0, 0);
    }

#pragma unroll
    for (int mt = 0; mt < 4; mt++) {
#pragma unroll
        for (int r = 0; r < 4; r++) {
            int row = ridx[wm + mt * 16 + rowg * 4 + r];
#pragma unroll
            for (int nt = 0; nt < 4; nt++) {
                int colg = n0 + wn + nt * 16 + col;
                float v = acc[mt][nt][r];
                if (out_bf16) ((short*)OUT)[(size_t)row * ldo + colg] = f2bf(v);
                else          ((float*)OUT)[(size_t)row * ldo + colg] = v;
            }
        }
    }
}

// ---------------------------------------------------------------------------
// Per-(row, head) RMSNorm + NeoX RoPE, bf16 in-place; oscale folds softmax
// scale for q. One wave / head.
// ---------------------------------------------------------------------------
__global__ __launch_bounds__(64)
void norm_rope(short* __restrict__ buf, const float* __restrict__ w,
               const int* __restrict__ positions, int ldrow, float oscale)
{
    const int row  = blockIdx.x;
    const int head = blockIdx.y;
    const int lane = threadIdx.x;

    short* p = buf + (size_t)row * ldrow + head * HD + lane;
    float x = bf2f(*p);

    float ss = x * x;
#pragma unroll
    for (int off = 32; off > 0; off >>= 1) ss += __shfl_xor(ss, off, 64);
    float rs = rsqrtf(ss * (1.0f / HD) + 1e-6f);
    float xn = x * rs * w[lane];

    int   j  = lane & 31;
    float inv_freq = powf(10000.0f, -(float)j * (1.0f / 32.0f));
    float fr = (float)positions[row] * inv_freq;
    float c = cosf(fr), s = sinf(fr);

    float partner = __shfl_xor(xn, 32, 64);
    float out = (lane < 32) ? (xn * c - partner * s) : (xn * c + partner * s);
    *p = f2bf(out * oscale);
}

// ---------------------------------------------------------------------------
// MFMA flash attention, all-bf16 inputs (q pre-scaled, V pre-transposed).
// Core MFMA/softmax logic unchanged from verified R1-R3 version.
// ---------------------------------------------------------------------------
__global__ __launch_bounds__(256)
void attn_mfma(const short* __restrict__ qb, const short* __restrict__ kb,
               const short* __restrict__ vt, const int* __restrict__ positions,
               short* __restrict__ ob)
{
    __shared__ __align__(16) short Ks[32][72];    // [krow][d] pad 8
    __shared__ __align__(16) short Vt[64][40];    // [d][krow] pad 8
    __shared__ __align__(16) short Ps[4][16][40];

    const int qt   = blockIdx.x;
    const int head = blockIdx.y;
    const int kvh  = head >> 2;
    const int q0   = qt * 64;
    const int t    = threadIdx.x;
    const int lane = t & 63;
    const int wave = t >> 6;
    const int rowg = lane >> 4;
    const int col  = lane & 15;
    const int m0   = q0 + wave * 16;

    // Q A-frags: direct bf16 loads (scale folded into norm_rope)
    const short* qrow = qb + (size_t)(m0 + col) * HID + head * HD;
    short8 aq0 = *(const short8*)(qrow + rowg * 8);
    short8 aq1 = *(const short8*)(qrow + 32 + rowg * 8);

    float m_i[4], l_i[4];
    int   pq[4];
#pragma unroll
    for (int r = 0; r < 4; r++) {
        m_i[r] = -3e38f; l_i[r] = 0.f;
        pq[r] = positions[m0 + rowg * 4 + r];
    }
    float4v oacc[4];
#pragma unroll
    for (int n = 0; n < 4; n++) oacc[n] = (float4v){0.f, 0.f, 0.f, 0.f};

    const int krow = t >> 3;           // K staging: 0..31
    const int d0   = (t & 7) * 8;
    const int dv   = t >> 2;           // V staging: 0..63
    const int kr0  = (t & 3) * 8;
    const int nkt  = 2 * qt + 2;

    for (int kt = 0; kt < nkt; kt++) {
        const int k0 = kt * 32;
        __syncthreads();

        *(short8*)&Ks[krow][d0] =
            *(const short8*)(kb + (size_t)(k0 + krow) * 1024 + kvh * HD + d0);
        *(short8*)&Vt[dv][kr0] =
            *(const short8*)(vt + ((size_t)kvh * HD + dv) * N_TOK + k0 + kr0);
        __syncthreads();

        const bool active = (k0 <= m0 + 15);
        float alpha[4];

        if (active) {
            short8 bk00 = *(const short8*)&Ks[col][rowg * 8];
            short8 bk01 = *(const short8*)&Ks[col][32 + rowg * 8];
            short8 bk10 = *(const short8*)&Ks[16 + col][rowg * 8];
            short8 bk11 = *(const short8*)&Ks[16 + col][32 + rowg * 8];
            float4v c0 = (float4v){0.f, 0.f, 0.f, 0.f};
            float4v c1 = (float4v){0.f, 0.f, 0.f, 0.f};
            c0 = __builtin_amdgcn_mfma_f32_16x16x32_bf16(aq0, bk00, c0, 0, 0, 0);
            c0 = __builtin_amdgcn_mfma_f32_16x16x32_bf16(aq1, bk01, c0, 0, 0, 0);
            c1 = __builtin_amdgcn_mfma_f32_16x16x32_bf16(aq0, bk10, c1, 0, 0, 0);
            c1 = __builtin_amdgcn_mfma_f32_16x16x32_bf16(aq1, bk11, c1, 0, 0, 0);

            const int pk0 = positions[k0 + col];
            const int pk1 = positions[k0 + 16 + col];
            float s0[4], s1[4], mt[4], psum[4];
#pragma unroll
            for (int r = 0; r < 4; r++) {
                s0[r] = (pq[r] >= pk0) ? c0[r] : -3e38f;
                s1[r] = (pq[r] >= pk1) ? c1[r] : -3e38f;
                mt[r] = fmaxf(s0[r], s1[r]);
            }
#pragma unroll
            for (int off = 1; off < 16; off <<= 1)
#pragma unroll
                for (int r = 0; r < 4; r++)
                    mt[r] = fmaxf(mt[r], __shfl_xor(mt[r], off, 64));
#pragma unroll
            for (int r = 0; r < 4; r++) {
                mt[r] = fmaxf(mt[r], m_i[r]);
                alpha[r] = __expf(m_i[r] - mt[r]);
                m_i[r] = mt[r];
                float p0 = __expf(s0[r] - mt[r]);
                float p1 = __expf(s1[r] - mt[r]);
                Ps[wave][rowg * 4 + r][col]      = f2bf(p0);
                Ps[wave][rowg * 4 + r][16 + col] = f2bf(p1);
                psum[r] = p0 + p1;
            }
#pragma unroll
            for (int off = 1; off < 16; off <<= 1)
#pragma unroll
                for (int r = 0; r < 4; r++)
                    psum[r] += __shfl_xor(psum[r], off, 64);
#pragma unroll
            for (int r = 0; r < 4; r++)
                l_i[r] = l_i[r] * alpha[r] + psum[r];
        }

        __syncthreads();

        if (active) {
            short8 ap = *(const short8*)&Ps[wave][col][rowg * 8];
#pragma unroll
            for (int n = 0; n < 4; n++) {
                short8 bv = *(const short8*)&Vt[n * 16 + col][rowg * 8];
                float4v acc2 = oacc[n];
#pragma unroll
                for (int r = 0; r < 4; r++) acc2[r] *= alpha[r];
                acc2 = __builtin_amdgcn_mfma_f32_16x16x32_bf16(ap, bv, acc2, 0, 0, 0);
                oacc[n] = acc2;
            }
        }
    }

    float linv[4];
#pragma unroll
    for (int r = 0; r < 4; r++) linv[r] = 1.f / l_i[r];
#pragma unroll
    for (int n = 0; n < 4; n++)
#pragma unroll
        for (int r = 0; r < 4; r++)
            ob[(size_t)(m0 + rowg * 4 + r) * HID + head * HD + n * 16 + col] =
                f2bf(oacc[n][r] * linv[r]);
}

// ---------------------------------------------------------------------------
extern "C" void kernel_launch(void* const* d_in, const int* in_sizes, int n_in,
                              void* d_out, int out_size, void* d_ws, size_t ws_size,
                              hipStream_t stream)
{
    (void)in_sizes; (void)n_in; (void)out_size; (void)ws_size;

    const float* hidden    = (const float*)d_in[0];
    const int*   positions = (const int*)  d_in[1];
    const int*   sort_idx  = (const int*)  d_in[2];
    const float* q_proj_w  = (const float*)d_in[3];
    const float* o_proj_w  = (const float*)d_in[4];
    const float* k_w       = (const float*)d_in[5];
    const float* v_w       = (const float*)d_in[6];
    const float* q_norm_w  = (const float*)d_in[7];
    const float* k_norm_w  = (const float*)d_in[8];
    float* out = (float*)d_out;

    // ws layout (shorts): Wqo 16M | Wkv 2M | Xbf 4M (later o_bf) | qb 4M |
    // kvb 2M | vt 1M  == 58 MB
    const size_t M1 = 1024 * 1024;
    short* Wqo = (short*)d_ws;
    short* Wkv = Wqo + 16 * M1;
    short* Xbf = Wkv + 2 * M1;
    short* qb  = Xbf + 4 * M1;
    short* kvb = qb  + 4 * M1;
    short* vt  = kvb + 2 * M1;
    short* obf = Xbf;   // alias: Xbf dead after the q/kv GEMMs

    cvt_bf16<<<2048, 256, 0, stream>>>(hidden, Xbf);
    wtrans<<<dim3(32, 32, 4), 256, 0, stream>>>(q_proj_w, Wqo, 2048);
    wtrans<<<dim3(32, 8, 1),  256, 0, stream>>>(k_w, Wkv, 512);
    wtrans<<<dim3(32, 8, 1),  256, 0, stream>>>(v_w, Wkv + (size_t)512 * 2048, 512);

    gemm_bf16<<<dim3(16, 16), 256, 0, stream>>>(Xbf, Wqo, sort_idx, qb, 2048, 2048, 1, 1);
    gemm_bf16<<<dim3(8, 16),  256, 0, stream>>>(Xbf, Wkv, nullptr, kvb, 1024, 1024, 0, 1);

    norm_rope<<<dim3(N_TOK, NH),  64, 0, stream>>>(qb,  q_norm_w, positions, 2048, 0.125f);
    norm_rope<<<dim3(N_TOK, NKV), 64, 0, stream>>>(kvb, k_norm_w, positions, 1024, 1.0f);
    vtrans<<<dim3(32, 8), 256, 0, stream>>>(kvb + 512, vt, 1024);

    wtrans<<<dim3(32, 32, 4), 256, 0, stream>>>(o_proj_w, Wqo, 2048);  // after q-GEMM

    attn_mfma<<<dim3(N_TOK / 64, NH), 256, 0, stream>>>(qb, kvb, vt, positions, obf);

    gemm_bf16<<<dim3(16, 16), 256, 0, stream>>>(obf, Wqo, sort_idx, out, 2048, 2048, 1, 0);
}

// Round 5
// 405.863 us; speedup vs baseline: 6.5508x; 1.2848x over previous
//
#include <hip/hip_runtime.h>
#include <hip/hip_bf16.h>

#define N_TOK 2048
#define HID   2048
#define NH    32
#define NKV   8
#define HD    64
#define NEXP  4
#define CHUNK (N_TOK / NEXP)   // 512
#define KV_DIM (NKV * HD)      // 512

typedef __attribute__((ext_vector_type(8))) short short8;
typedef __attribute__((ext_vector_type(4))) float float4v;

__device__ inline short f2bf(float f) {
    __hip_bfloat16 h = __float2bfloat16(f);
    return *reinterpret_cast<short*>(&h);
}
__device__ inline float bf2f(short s) {
    __hip_bfloat16 h = *reinterpret_cast<__hip_bfloat16*>(&s);
    return __bfloat162float(h);
}

// ---------------------------------------------------------------------------
// fp32 -> bf16 convert, 8 elems/thread.
// ---------------------------------------------------------------------------
__global__ __launch_bounds__(256)
void cvt_bf16(const float* __restrict__ in, short* __restrict__ out)
{
    size_t i = (size_t)blockIdx.x * 256 + threadIdx.x;
    float4 a = ((const float4*)in)[i * 2];
    float4 b = ((const float4*)in)[i * 2 + 1];
    short8 s;
    s[0] = f2bf(a.x); s[1] = f2bf(a.y); s[2] = f2bf(a.z); s[3] = f2bf(a.w);
    s[4] = f2bf(b.x); s[5] = f2bf(b.y); s[6] = f2bf(b.z); s[7] = f2bf(b.w);
    ((short8*)out)[i] = s;
}

// ---------------------------------------------------------------------------
// Weight transpose+convert: fp32 [E][K=2048][Nw] -> bf16 [E][Nw][2048].
// ---------------------------------------------------------------------------
__global__ __launch_bounds__(256)
void wtrans(const float* __restrict__ in, short* __restrict__ out, int Nw)
{
    __shared__ float T[64][65];
    const int k0 = blockIdx.x * 64, n0 = blockIdx.y * 64;
    const size_t eoff = (size_t)blockIdx.z * 2048 * (size_t)Nw;
    const int t = threadIdx.x;
#pragma unroll
    for (int i = 0; i < 16; i++) {
        int idx = t + i * 256, kl = idx >> 6, nl = idx & 63;
        T[kl][nl] = in[eoff + (size_t)(k0 + kl) * Nw + n0 + nl];
    }
    __syncthreads();
#pragma unroll
    for (int i = 0; i < 16; i++) {
        int idx = t + i * 256, nl = idx >> 6, kl = idx & 63;
        out[eoff + (size_t)(n0 + nl) * 2048 + k0 + kl] = f2bf(T[kl][nl]);
    }
}

// ---------------------------------------------------------------------------
// V transpose (bf16): in [N][ldrow] (v cols pre-offset) -> out [HD*NKV][N].
// ---------------------------------------------------------------------------
__global__ __launch_bounds__(256)
void vtrans(const short* __restrict__ v, short* __restrict__ vt, int ldrow)
{
    __shared__ short T[64][66];
    const int n0 = blockIdx.x * 64, h = blockIdx.y;
    const int t = threadIdx.x;
#pragma unroll
    for (int i = 0; i < 16; i++) {
        int idx = t + i * 256, nl = idx >> 6, dl = idx & 63;
        T[nl][dl] = v[(size_t)(n0 + nl) * ldrow + h * HD + dl];
    }
    __syncthreads();
#pragma unroll
    for (int i = 0; i < 16; i++) {
        int idx = t + i * 256, dl = idx >> 6, nl = idx & 63;
        vt[((size_t)h * HD + dl) * N_TOK + n0 + nl] = T[nl][dl];
    }
}

// ---------------------------------------------------------------------------
// bf16 MFMA GEMM, 128x128 tile, BK=32, 4 waves, LDS-staged. (unchanged R4)
// ---------------------------------------------------------------------------
__global__ __launch_bounds__(256)
void gemm_bf16(const short* __restrict__ X, const short* __restrict__ Wt,
               const int* __restrict__ sidx, void* __restrict__ OUT,
               int N, int ldo, int routed, int out_bf16)
{
    __shared__ __align__(16) short As[128 * 32];
    __shared__ __align__(16) short Bs[128 * 32];
    __shared__ int ridx[128];

    const int t  = threadIdx.x;
    const int m0 = blockIdx.y * 128;
    const int n0 = blockIdx.x * 128;

    if (t < 128) ridx[t] = routed ? sidx[m0 + t] : (m0 + t);

    const short* Wb = Wt + (routed ? (size_t)(m0 / CHUNK) * (size_t)N * 2048 : 0);

    const int q4 = t & 3;
    __syncthreads();
    const short* pa0 = X + (size_t)ridx[t >> 2] * 2048 + q4 * 8;
    const short* pa1 = X + (size_t)ridx[64 + (t >> 2)] * 2048 + q4 * 8;
    const short* pb0 = Wb + (size_t)(n0 + (t >> 2)) * 2048 + q4 * 8;
    const short* pb1 = Wb + (size_t)(n0 + 64 + (t >> 2)) * 2048 + q4 * 8;

    const int lane = t & 63;
    const int wave = t >> 6;
    const int col  = lane & 15;
    const int rowg = lane >> 4;
    const int wm   = (wave >> 1) * 64;
    const int wn   = (wave & 1) * 64;

    int offA[4], offB[4];
#pragma unroll
    for (int i = 0; i < 4; i++) {
        offA[i] = (wm + i * 16 + col) * 32 + rowg * 8;
        offB[i] = (wn + i * 16 + col) * 32 + rowg * 8;
    }

    float4v acc[4][4];
#pragma unroll
    for (int mt = 0; mt < 4; mt++)
#pragma unroll
        for (int nt = 0; nt < 4; nt++) acc[mt][nt] = (float4v){0.f, 0.f, 0.f, 0.f};

    for (int k0 = 0; k0 < 2048; k0 += 32) {
        short8 a0 = *(const short8*)(pa0 + k0);
        short8 a1 = *(const short8*)(pa1 + k0);
        short8 b0 = *(const short8*)(pb0 + k0);
        short8 b1 = *(const short8*)(pb1 + k0);
        __syncthreads();
        *(short8*)&As[t * 8]          = a0;
        *(short8*)&As[(t + 256) * 8]  = a1;
        *(short8*)&Bs[t * 8]          = b0;
        *(short8*)&Bs[(t + 256) * 8]  = b1;
        __syncthreads();

        short8 af[4], bfr[4];
#pragma unroll
        for (int i = 0; i < 4; i++) af[i] = *(const short8*)&As[offA[i]];
#pragma unroll
        for (int i = 0; i < 4; i++) bfr[i] = *(const short8*)&Bs[offB[i]];
#pragma unroll
        for (int mt = 0; mt < 4; mt++)
#pragma unroll
            for (int nt = 0; nt < 4; nt++)
                acc[mt][nt] = __builtin_amdgcn_mfma_f32_16x16x32_bf16(
                    af[mt], bfr[nt], acc[mt][nt], 0, 0, 0);
    }

#pragma unroll
    for (int mt = 0; mt < 4; mt++) {
#pragma unroll
        for (int r = 0; r < 4; r++) {
            int row = ridx[wm + mt * 16 + rowg * 4 + r];
#pragma unroll
            for (int nt = 0; nt < 4; nt++) {
                int colg = n0 + wn + nt * 16 + col;
                float v = acc[mt][nt][r];
                if (out_bf16) ((short*)OUT)[(size_t)row * ldo + colg] = f2bf(v);
                else          ((float*)OUT)[(size_t)row * ldo + colg] = v;
            }
        }
    }
}

// ---------------------------------------------------------------------------
// Per-(row, head) RMSNorm + NeoX RoPE, bf16 in-place; oscale folds softmax
// scale for q.
// ---------------------------------------------------------------------------
__global__ __launch_bounds__(64)
void norm_rope(short* __restrict__ buf, const float* __restrict__ w,
               const int* __restrict__ positions, int ldrow, float oscale)
{
    const int row  = blockIdx.x;
    const int head = blockIdx.y;
    const int lane = threadIdx.x;

    short* p = buf + (size_t)row * ldrow + head * HD + lane;
    float x = bf2f(*p);

    float ss = x * x;
#pragma unroll
    for (int off = 32; off > 0; off >>= 1) ss += __shfl_xor(ss, off, 64);
    float rs = rsqrtf(ss * (1.0f / HD) + 1e-6f);
    float xn = x * rs * w[lane];

    int   j  = lane & 31;
    float inv_freq = powf(10000.0f, -(float)j * (1.0f / 32.0f));
    float fr = (float)positions[row] * inv_freq;
    float c = cosf(fr), s = sinf(fr);

    float partner = __shfl_xor(xn, 32, 64);
    float out = (lane < 32) ? (xn * c - partner * s) : (xn * c + partner * s);
    *p = f2bf(out * oscale);
}

// ---------------------------------------------------------------------------
// MFMA flash attention v2: K-tile 64, FIXED-max softmax (||q̂||<=1, ||k||<=8
// after RMSNorm+RoPE => s<=8<9; p=exp(s-9) is exact softmax, no online
// rescale), paired q-tiles (qt, 31-qt) for perfect 33-tile/block balance.
// Block = 4 waves x 16 q-rows, 1 head. All waves active in all tiles.
// ---------------------------------------------------------------------------
__global__ __launch_bounds__(256)
void attn_mfma(const short* __restrict__ qb, const short* __restrict__ kb,
               const short* __restrict__ vt, const int* __restrict__ positions,
               short* __restrict__ ob)
{
    __shared__ __align__(16) short Ks[64][72];     // [krow][d]   pad 8
    __shared__ __align__(16) short Vt[64][72];     // [d][krow]   pad 8
    __shared__ __align__(16) short Ps[4][16][72];  // per-wave P  pad 8

    const int head = blockIdx.y;
    const int kvh  = head >> 2;
    const int t    = threadIdx.x;
    const int lane = t & 63;
    const int wave = t >> 6;
    const int rowg = lane >> 4;
    const int col  = lane & 15;

    const int sr = t >> 2;          // staging row 0..63
    const int sc = (t & 3) * 16;    // staging col 0,16,32,48

#pragma unroll
    for (int pass = 0; pass < 2; pass++) {
        const int qt = pass == 0 ? (31 - (int)blockIdx.x) : (int)blockIdx.x;
        const int q0 = qt * 64;
        const int m0 = q0 + wave * 16;

        const short* qrow = qb + (size_t)(m0 + col) * HID + head * HD;
        short8 aq0 = *(const short8*)(qrow + rowg * 8);
        short8 aq1 = *(const short8*)(qrow + 32 + rowg * 8);

        int pq[4];
        float l_i[4];
#pragma unroll
        for (int r = 0; r < 4; r++) {
            pq[r] = positions[m0 + rowg * 4 + r];
            l_i[r] = 0.f;
        }
        float4v oacc[4];
#pragma unroll
        for (int n = 0; n < 4; n++) oacc[n] = (float4v){0.f, 0.f, 0.f, 0.f};

        const int nkt = qt + 1;
        for (int kt = 0; kt < nkt; kt++) {
            const int k0 = kt * 64;
            __syncthreads();   // previous tile's Ks/Vt reads done
            {
                const short* kp = kb + (size_t)(k0 + sr) * 1024 + kvh * HD + sc;
                const short* vp = vt + ((size_t)kvh * HD + sr) * N_TOK + k0 + sc;
                short8 kA = *(const short8*)(kp);
                short8 kB = *(const short8*)(kp + 8);
                short8 vA = *(const short8*)(vp);
                short8 vB = *(const short8*)(vp + 8);
                *(short8*)&Ks[sr][sc]     = kA;
                *(short8*)&Ks[sr][sc + 8] = kB;
                *(short8*)&Vt[sr][sc]     = vA;
                *(short8*)&Vt[sr][sc + 8] = vB;
            }
            __syncthreads();   // tile staged

            // --- QK^T: 16 rows x 64 cols, 4 col-tiles x K=64 ---
            float4v c[4];
#pragma unroll
            for (int j = 0; j < 4; j++) {
                short8 blo = *(const short8*)&Ks[j * 16 + col][rowg * 8];
                short8 bhi = *(const short8*)&Ks[j * 16 + col][32 + rowg * 8];
                float4v cc = (float4v){0.f, 0.f, 0.f, 0.f};
                cc = __builtin_amdgcn_mfma_f32_16x16x32_bf16(aq0, blo, cc, 0, 0, 0);
                cc = __builtin_amdgcn_mfma_f32_16x16x32_bf16(aq1, bhi, cc, 0, 0, 0);
                c[j] = cc;
            }

            if (kt == qt) {   // only the diagonal tile needs masking
#pragma unroll
                for (int j = 0; j < 4; j++) {
                    int pk = positions[k0 + j * 16 + col];
#pragma unroll
                    for (int r = 0; r < 4; r++)
                        if (pq[r] < pk) c[j][r] = -1e30f;
                }
            }

            // --- fixed-max softmax: p = exp(s - 9), exact ---
#pragma unroll
            for (int j = 0; j < 4; j++)
#pragma unroll
                for (int r = 0; r < 4; r++) {
                    float p = __expf(c[j][r] - 9.0f);
                    l_i[r] += p;
                    Ps[wave][rowg * 4 + r][j * 16 + col] = f2bf(p);
                }

            // Ps is wave-private: only need in-wave LDS ordering, no barrier
            __asm__ volatile("s_waitcnt lgkmcnt(0)" ::: "memory");

            // --- PV: O += P(16x64) @ V(64x64) ---
            short8 ap0 = *(const short8*)&Ps[wave][col][rowg * 8];
            short8 ap1 = *(const short8*)&Ps[wave][col][32 + rowg * 8];
#pragma unroll
            for (int n = 0; n < 4; n++) {
                short8 blo = *(const short8*)&Vt[n * 16 + col][rowg * 8];
                short8 bhi = *(const short8*)&Vt[n * 16 + col][32 + rowg * 8];
                float4v a2 = oacc[n];
                a2 = __builtin_amdgcn_mfma_f32_16x16x32_bf16(ap0, blo, a2, 0, 0, 0);
                a2 = __builtin_amdgcn_mfma_f32_16x16x32_bf16(ap1, bhi, a2, 0, 0, 0);
                oacc[n] = a2;
            }
        }

        // one l-reduction per pass (16-lane col groups)
#pragma unroll
        for (int r = 0; r < 4; r++) {
#pragma unroll
            for (int off = 1; off < 16; off <<= 1)
                l_i[r] += __shfl_xor(l_i[r], off, 64);
            l_i[r] = 1.f / l_i[r];
        }
#pragma unroll
        for (int n = 0; n < 4; n++)
#pragma unroll
            for (int r = 0; r < 4; r++)
                ob[(size_t)(m0 + rowg * 4 + r) * HID + head * HD + n * 16 + col] =
                    f2bf(oacc[n][r] * l_i[r]);
    }
}

// ---------------------------------------------------------------------------
extern "C" void kernel_launch(void* const* d_in, const int* in_sizes, int n_in,
                              void* d_out, int out_size, void* d_ws, size_t ws_size,
                              hipStream_t stream)
{
    (void)in_sizes; (void)n_in; (void)out_size; (void)ws_size;

    const float* hidden    = (const float*)d_in[0];
    const int*   positions = (const int*)  d_in[1];
    const int*   sort_idx  = (const int*)  d_in[2];
    const float* q_proj_w  = (const float*)d_in[3];
    const float* o_proj_w  = (const float*)d_in[4];
    const float* k_w       = (const float*)d_in[5];
    const float* v_w       = (const float*)d_in[6];
    const float* q_norm_w  = (const float*)d_in[7];
    const float* k_norm_w  = (const float*)d_in[8];
    float* out = (float*)d_out;

    const size_t M1 = 1024 * 1024;
    short* Wqo = (short*)d_ws;
    short* Wkv = Wqo + 16 * M1;
    short* Xbf = Wkv + 2 * M1;
    short* qb  = Xbf + 4 * M1;
    short* kvb = qb  + 4 * M1;
    short* vt  = kvb + 2 * M1;
    short* obf = Xbf;   // alias: Xbf dead after the q/kv GEMMs

    cvt_bf16<<<2048, 256, 0, stream>>>(hidden, Xbf);
    wtrans<<<dim3(32, 32, 4), 256, 0, stream>>>(q_proj_w, Wqo, 2048);
    wtrans<<<dim3(32, 8, 1),  256, 0, stream>>>(k_w, Wkv, 512);
    wtrans<<<dim3(32, 8, 1),  256, 0, stream>>>(v_w, Wkv + (size_t)512 * 2048, 512);

    gemm_bf16<<<dim3(16, 16), 256, 0, stream>>>(Xbf, Wqo, sort_idx, qb, 2048, 2048, 1, 1);
    gemm_bf16<<<dim3(8, 16),  256, 0, stream>>>(Xbf, Wkv, nullptr, kvb, 1024, 1024, 0, 1);

    norm_rope<<<dim3(N_TOK, NH),  64, 0, stream>>>(qb,  q_norm_w, positions, 2048, 0.125f);
    norm_rope<<<dim3(N_TOK, NKV), 64, 0, stream>>>(kvb, k_norm_w, positions, 1024, 1.0f);
    vtrans<<<dim3(32, 8), 256, 0, stream>>>(kvb + 512, vt, 1024);

    wtrans<<<dim3(32, 32, 4), 256, 0, stream>>>(o_proj_w, Wqo, 2048);  // after q-GEMM

    attn_mfma<<<dim3(16, NH), 256, 0, stream>>>(qb, kvb, vt, positions, obf);

    gemm_bf16<<<dim3(16, 16), 256, 0, stream>>>(obf, Wqo, sort_idx, out, 2048, 2048, 1, 0);
}

// Round 6
// 362.976 us; speedup vs baseline: 7.3248x; 1.1182x over previous
//
#include <hip/hip_runtime.h>
#include <hip/hip_bf16.h>

#define N_TOK 2048
#define HID   2048
#define NH    32
#define NKV   8
#define HD    64
#define NEXP  4
#define CHUNK (N_TOK / NEXP)   // 512
#define KV_DIM (NKV * HD)      // 512

typedef __attribute__((ext_vector_type(8))) short short8;
typedef __attribute__((ext_vector_type(4))) float float4v;

__device__ inline short f2bf(float f) {
    __hip_bfloat16 h = __float2bfloat16(f);
    return *reinterpret_cast<short*>(&h);
}
__device__ inline float bf2f(short s) {
    __hip_bfloat16 h = *reinterpret_cast<__hip_bfloat16*>(&s);
    return __bfloat162float(h);
}

// async global->LDS, 16 B per lane; lptr must be wave-uniform base, HW puts
// lane i at lptr + i*16 (m104 caveat).
__device__ __forceinline__ void gld_lds16(const void* g, void* l) {
    __builtin_amdgcn_global_load_lds(
        (const __attribute__((address_space(1))) unsigned int*)g,
        (__attribute__((address_space(3))) unsigned int*)l, 16, 0, 0);
}

// ---------------------------------------------------------------------------
// fp32 -> bf16 convert, 8 elems/thread.
// ---------------------------------------------------------------------------
__global__ __launch_bounds__(256)
void cvt_bf16(const float* __restrict__ in, short* __restrict__ out)
{
    size_t i = (size_t)blockIdx.x * 256 + threadIdx.x;
    float4 a = ((const float4*)in)[i * 2];
    float4 b = ((const float4*)in)[i * 2 + 1];
    short8 s;
    s[0] = f2bf(a.x); s[1] = f2bf(a.y); s[2] = f2bf(a.z); s[3] = f2bf(a.w);
    s[4] = f2bf(b.x); s[5] = f2bf(b.y); s[6] = f2bf(b.z); s[7] = f2bf(b.w);
    ((short8*)out)[i] = s;
}

// ---------------------------------------------------------------------------
// Weight transpose+convert: fp32 [E][K=2048][Nw] -> bf16 [E][Nw][2048].
// ---------------------------------------------------------------------------
__global__ __launch_bounds__(256)
void wtrans(const float* __restrict__ in, short* __restrict__ out, int Nw)
{
    __shared__ float T[64][65];
    const int k0 = blockIdx.x * 64, n0 = blockIdx.y * 64;
    const size_t eoff = (size_t)blockIdx.z * 2048 * (size_t)Nw;
    const int t = threadIdx.x;
#pragma unroll
    for (int i = 0; i < 16; i++) {
        int idx = t + i * 256, kl = idx >> 6, nl = idx & 63;
        T[kl][nl] = in[eoff + (size_t)(k0 + kl) * Nw + n0 + nl];
    }
    __syncthreads();
#pragma unroll
    for (int i = 0; i < 16; i++) {
        int idx = t + i * 256, nl = idx >> 6, kl = idx & 63;
        out[eoff + (size_t)(n0 + nl) * 2048 + k0 + kl] = f2bf(T[kl][nl]);
    }
}

// k_w and v_w transposed in one dispatch (z=0 -> k, z=1 -> v).
__global__ __launch_bounds__(256)
void wtrans_kv(const float* __restrict__ kw, const float* __restrict__ vw,
               short* __restrict__ out)
{
    __shared__ float T[64][65];
    const int k0 = blockIdx.x * 64, n0 = blockIdx.y * 64;
    const float* in = blockIdx.z ? vw : kw;
    short* o = out + (size_t)blockIdx.z * 512 * 2048;
    const int t = threadIdx.x;
#pragma unroll
    for (int i = 0; i < 16; i++) {
        int idx = t + i * 256, kl = idx >> 6, nl = idx & 63;
        T[kl][nl] = in[(size_t)(k0 + kl) * 512 + n0 + nl];
    }
    __syncthreads();
#pragma unroll
    for (int i = 0; i < 16; i++) {
        int idx = t + i * 256, nl = idx >> 6, kl = idx & 63;
        o[(size_t)(n0 + nl) * 2048 + k0 + kl] = f2bf(T[kl][nl]);
    }
}

// ---------------------------------------------------------------------------
// V transpose (bf16): in [N][ldrow] (v cols pre-offset) -> out [HD*NKV][N].
// ---------------------------------------------------------------------------
__global__ __launch_bounds__(256)
void vtrans(const short* __restrict__ v, short* __restrict__ vt, int ldrow)
{
    __shared__ short T[64][66];
    const int n0 = blockIdx.x * 64, h = blockIdx.y;
    const int t = threadIdx.x;
#pragma unroll
    for (int i = 0; i < 16; i++) {
        int idx = t + i * 256, nl = idx >> 6, dl = idx & 63;
        T[nl][dl] = v[(size_t)(n0 + nl) * ldrow + h * HD + dl];
    }
    __syncthreads();
#pragma unroll
    for (int i = 0; i < 16; i++) {
        int idx = t + i * 256, dl = idx >> 6, nl = idx & 63;
        vt[((size_t)h * HD + dl) * N_TOK + n0 + nl] = T[nl][dl];
    }
}

// ---------------------------------------------------------------------------
// bf16 MFMA GEMM core: 128x128 tile, BK=32, 4 waves, m97-style
// global_load_lds(16B) staging. X bf16 [rows][2048] (rows via sidx when
// routed); Wt bf16 [E][N][2048] k-contiguous.
// ---------------------------------------------------------------------------
template <bool OUT_F32>
__device__ __forceinline__ void gemm_core(
    const short* __restrict__ X, const short* __restrict__ Wt,
    const int* __restrict__ sidx, void* __restrict__ OUT,
    int dout, bool routed, int bx, int by,
    short* As, short* Bs, int* ridx)
{
    const int t  = threadIdx.x;
    const int m0 = by * 128;
    const int n0 = bx * 128;

    if (t < 128) ridx[t] = routed ? sidx[m0 + t] : (m0 + t);
    __syncthreads();

    const short* Wb = Wt + (routed ? (size_t)(m0 / CHUNK) * (size_t)dout * 2048 : 0);

    const int seg = (t & 3) * 8;
    const short* ga0 = X  + (size_t)ridx[t >> 2] * 2048 + seg;
    const short* ga1 = X  + (size_t)ridx[64 + (t >> 2)] * 2048 + seg;
    const short* gb0 = Wb + (size_t)(n0 + (t >> 2)) * 2048 + seg;
    const short* gb1 = Wb + (size_t)(n0 + 64 + (t >> 2)) * 2048 + seg;

    const int lane = t & 63;
    const int wave = t >> 6;
    // wave-uniform LDS bases; lane i lands at +i*16B == As[(wave*64+lane)*8]
    short* lA0 = As + (size_t)(wave * 64) * 8;
    short* lA1 = As + (size_t)(256 + wave * 64) * 8;
    short* lB0 = Bs + (size_t)(wave * 64) * 8;
    short* lB1 = Bs + (size_t)(256 + wave * 64) * 8;

    const int col  = lane & 15;
    const int rowg = lane >> 4;
    const int wm   = (wave >> 1) * 64;
    const int wn   = (wave & 1) * 64;

    int offA[4], offB[4];
#pragma unroll
    for (int i = 0; i < 4; i++) {
        offA[i] = (wm + i * 16 + col) * 32 + rowg * 8;
        offB[i] = (wn + i * 16 + col) * 32 + rowg * 8;
    }

    float4v acc[4][4];
#pragma unroll
    for (int mt = 0; mt < 4; mt++)
#pragma unroll
        for (int nt = 0; nt < 4; nt++) acc[mt][nt] = (float4v){0.f, 0.f, 0.f, 0.f};

    for (int k0 = 0; k0 < 2048; k0 += 32) {
        __syncthreads();               // prev frag reads done; LDS writable
        gld_lds16(ga0 + k0, lA0);
        gld_lds16(ga1 + k0, lA1);
        gld_lds16(gb0 + k0, lB0);
        gld_lds16(gb1 + k0, lB1);
        __syncthreads();               // barrier drains vmcnt: tile in LDS

        short8 af[4], bfr[4];
#pragma unroll
        for (int i = 0; i < 4; i++) af[i] = *(const short8*)&As[offA[i]];
#pragma unroll
        for (int i = 0; i < 4; i++) bfr[i] = *(const short8*)&Bs[offB[i]];
#pragma unroll
        for (int mt = 0; mt < 4; mt++)
#pragma unroll
            for (int nt = 0; nt < 4; nt++)
                acc[mt][nt] = __builtin_amdgcn_mfma_f32_16x16x32_bf16(
                    af[mt], bfr[nt], acc[mt][nt], 0, 0, 0);
    }

#pragma unroll
    for (int mt = 0; mt < 4; mt++) {
#pragma unroll
        for (int r = 0; r < 4; r++) {
            int row = ridx[wm + mt * 16 + rowg * 4 + r];
#pragma unroll
            for (int nt = 0; nt < 4; nt++) {
                int colg = n0 + wn + nt * 16 + col;
                float v = acc[mt][nt][r];
                if (OUT_F32) ((float*)OUT)[(size_t)row * dout + colg] = v;
                else         ((short*)OUT)[(size_t)row * dout + colg] = f2bf(v);
            }
        }
    }
}

// fused q-proj (256 blocks, routed) + kv-proj (128 blocks) in one dispatch
__global__ __launch_bounds__(256)
void gemm_qkv(const short* __restrict__ X, const short* __restrict__ Wq,
              const short* __restrict__ Wkv, const int* __restrict__ sidx,
              short* __restrict__ qout, short* __restrict__ kvout)
{
    __shared__ __align__(16) short As[128 * 32];
    __shared__ __align__(16) short Bs[128 * 32];
    __shared__ int ridx[128];
    int b = blockIdx.x;
    if (b < 256)
        gemm_core<false>(X, Wq, sidx, qout, 2048, true, b & 15, b >> 4, As, Bs, ridx);
    else {
        b -= 256;
        gemm_core<false>(X, Wkv, nullptr, kvout, 1024, false, b & 7, b >> 3, As, Bs, ridx);
    }
}

__global__ __launch_bounds__(256)
void gemm_o(const short* __restrict__ X, const short* __restrict__ Wt,
            const int* __restrict__ sidx, float* __restrict__ OUT)
{
    __shared__ __align__(16) short As[128 * 32];
    __shared__ __align__(16) short Bs[128 * 32];
    __shared__ int ridx[128];
    gemm_core<true>(X, Wt, sidx, OUT, 2048, true, blockIdx.x, blockIdx.y, As, Bs, ridx);
}

// ---------------------------------------------------------------------------
// Fused q+k RMSNorm + NeoX RoPE, bf16 in-place. blockIdx.y < NH -> q head
// (scale 0.125*log2e folded for exp2 softmax), else k head (scale 1).
// ---------------------------------------------------------------------------
__global__ __launch_bounds__(64)
void norm_rope_qk(short* __restrict__ qb, short* __restrict__ kvb,
                  const float* __restrict__ qw, const float* __restrict__ kw,
                  const int* __restrict__ positions)
{
    const int row  = blockIdx.x;
    const int h    = blockIdx.y;
    const int lane = threadIdx.x;

    short* p;
    const float* w;
    float oscale;
    if (h < NH) { p = qb + (size_t)row * 2048 + h * HD + lane; w = qw;
                  oscale = 0.125f * 1.44269504f; }
    else        { p = kvb + (size_t)row * 1024 + (h - NH) * HD + lane; w = kw;
                  oscale = 1.0f; }

    float x = bf2f(*p);
    float ss = x * x;
#pragma unroll
    for (int off = 32; off > 0; off >>= 1) ss += __shfl_xor(ss, off, 64);
    float rs = rsqrtf(ss * (1.0f / HD) + 1e-6f);
    float xn = x * rs * w[lane];

    int   j  = lane & 31;
    // inv_freq = 10000^(-j/32) = 2^(-j*log2(1e4)/32)
    float inv_freq = exp2f(-(float)j * 0.41524101186f);
    float fr = (float)positions[row] * inv_freq;
    float c = __cosf(fr), s = __sinf(fr);

    float partner = __shfl_xor(xn, 32, 64);
    float out = (lane < 32) ? (xn * c - partner * s) : (xn * c + partner * s);
    *p = f2bf(out * oscale);
}

// ---------------------------------------------------------------------------
// MFMA flash attention: K-tile 64, fixed-max softmax p = exp2(s' - 9*log2e)
// (exact: q pre-scaled by 0.125*log2e; |s_true|<=8 after RMSNorm+RoPE),
// paired q-tiles (qt, 31-qt) for perfect balance. (structure verified R5)
// ---------------------------------------------------------------------------
__global__ __launch_bounds__(256)
void attn_mfma(const short* __restrict__ qb, const short* __restrict__ kb,
               const short* __restrict__ vt, const int* __restrict__ positions,
               short* __restrict__ ob)
{
    __shared__ __align__(16) short Ks[64][72];
    __shared__ __align__(16) short Vt[64][72];
    __shared__ __align__(16) short Ps[4][16][72];

    const int head = blockIdx.y;
    const int kvh  = head >> 2;
    const int t    = threadIdx.x;
    const int lane = t & 63;
    const int wave = t >> 6;
    const int rowg = lane >> 4;
    const int col  = lane & 15;

    const int sr = t >> 2;
    const int sc = (t & 3) * 16;
    const float BIAS = 9.0f * 1.44269504f;   // 9*log2e, exp2 domain

#pragma unroll
    for (int pass = 0; pass < 2; pass++) {
        const int qt = pass == 0 ? (31 - (int)blockIdx.x) : (int)blockIdx.x;
        const int q0 = qt * 64;
        const int m0 = q0 + wave * 16;

        const short* qrow = qb + (size_t)(m0 + col) * HID + head * HD;
        short8 aq0 = *(const short8*)(qrow + rowg * 8);
        short8 aq1 = *(const short8*)(qrow + 32 + rowg * 8);

        int pq[4];
        float l_i[4];
#pragma unroll
        for (int r = 0; r < 4; r++) {
            pq[r] = positions[m0 + rowg * 4 + r];
            l_i[r] = 0.f;
        }
        float4v oacc[4];
#pragma unroll
        for (int n = 0; n < 4; n++) oacc[n] = (float4v){0.f, 0.f, 0.f, 0.f};

        const int nkt = qt + 1;
        for (int kt = 0; kt < nkt; kt++) {
            const int k0 = kt * 64;
            __syncthreads();
            {
                const short* kp = kb + (size_t)(k0 + sr) * 1024 + kvh * HD + sc;
                const short* vp = vt + ((size_t)kvh * HD + sr) * N_TOK + k0 + sc;
                short8 kA = *(const short8*)(kp);
                short8 kB = *(const short8*)(kp + 8);
                short8 vA = *(const short8*)(vp);
                short8 vB = *(const short8*)(vp + 8);
                *(short8*)&Ks[sr][sc]     = kA;
                *(short8*)&Ks[sr][sc + 8] = kB;
                *(short8*)&Vt[sr][sc]     = vA;
                *(short8*)&Vt[sr][sc + 8] = vB;
            }
            __syncthreads();

            float4v c[4];
#pragma unroll
            for (int j = 0; j < 4; j++) {
                short8 blo = *(const short8*)&Ks[j * 16 + col][rowg * 8];
                short8 bhi = *(const short8*)&Ks[j * 16 + col][32 + rowg * 8];
                float4v cc = (float4v){0.f, 0.f, 0.f, 0.f};
                cc = __builtin_amdgcn_mfma_f32_16x16x32_bf16(aq0, blo, cc, 0, 0, 0);
                cc = __builtin_amdgcn_mfma_f32_16x16x32_bf16(aq1, bhi, cc, 0, 0, 0);
                c[j] = cc;
            }

            if (kt == qt) {
#pragma unroll
                for (int j = 0; j < 4; j++) {
                    int pk = positions[k0 + j * 16 + col];
#pragma unroll
                    for (int r = 0; r < 4; r++)
                        if (pq[r] < pk) c[j][r] = -1e30f;
                }
            }

#pragma unroll
            for (int j = 0; j < 4; j++)
#pragma unroll
                for (int r = 0; r < 4; r++) {
                    float p = exp2f(c[j][r] - BIAS);
                    l_i[r] += p;
                    Ps[wave][rowg * 4 + r][j * 16 + col] = f2bf(p);
                }

            __asm__ volatile("s_waitcnt lgkmcnt(0)" ::: "memory");

            short8 ap0 = *(const short8*)&Ps[wave][col][rowg * 8];
            short8 ap1 = *(const short8*)&Ps[wave][col][32 + rowg * 8];
#pragma unroll
            for (int n = 0; n < 4; n++) {
                short8 blo = *(const short8*)&Vt[n * 16 + col][rowg * 8];
                short8 bhi = *(const short8*)&Vt[n * 16 + col][32 + rowg * 8];
                float4v a2 = oacc[n];
                a2 = __builtin_amdgcn_mfma_f32_16x16x32_bf16(ap0, blo, a2, 0, 0, 0);
                a2 = __builtin_amdgcn_mfma_f32_16x16x32_bf16(ap1, bhi, a2, 0, 0, 0);
                oacc[n] = a2;
            }
        }

#pragma unroll
        for (int r = 0; r < 4; r++) {
#pragma unroll
            for (int off = 1; off < 16; off <<= 1)
                l_i[r] += __shfl_xor(l_i[r], off, 64);
            l_i[r] = 1.f / l_i[r];
        }
#pragma unroll
        for (int n = 0; n < 4; n++)
#pragma unroll
            for (int r = 0; r < 4; r++)
                ob[(size_t)(m0 + rowg * 4 + r) * HID + head * HD + n * 16 + col] =
                    f2bf(oacc[n][r] * l_i[r]);
    }
}

// ---------------------------------------------------------------------------
extern "C" void kernel_launch(void* const* d_in, const int* in_sizes, int n_in,
                              void* d_out, int out_size, void* d_ws, size_t ws_size,
                              hipStream_t stream)
{
    (void)in_sizes; (void)n_in; (void)out_size; (void)ws_size;

    const float* hidden    = (const float*)d_in[0];
    const int*   positions = (const int*)  d_in[1];
    const int*   sort_idx  = (const int*)  d_in[2];
    const float* q_proj_w  = (const float*)d_in[3];
    const float* o_proj_w  = (const float*)d_in[4];
    const float* k_w       = (const float*)d_in[5];
    const float* v_w       = (const float*)d_in[6];
    const float* q_norm_w  = (const float*)d_in[7];
    const float* k_norm_w  = (const float*)d_in[8];
    float* out = (float*)d_out;

    const size_t M1 = 1024 * 1024;
    short* Wqo = (short*)d_ws;         // 32 MB (q weights, then o weights)
    short* Wkv = Wqo + 16 * M1;        // 4 MB
    short* Xbf = Wkv + 2 * M1;         // 8 MB (later aliased as obf)
    short* qb  = Xbf + 4 * M1;         // 8 MB
    short* kvb = qb  + 4 * M1;         // 4 MB
    short* vt  = kvb + 2 * M1;         // 2 MB
    short* obf = Xbf;

    cvt_bf16<<<2048, 256, 0, stream>>>(hidden, Xbf);
    wtrans<<<dim3(32, 32, 4), 256, 0, stream>>>(q_proj_w, Wqo, 2048);
    wtrans_kv<<<dim3(32, 8, 2), 256, 0, stream>>>(k_w, v_w, Wkv);

    gemm_qkv<<<384, 256, 0, stream>>>(Xbf, Wqo, Wkv, sort_idx, qb, kvb);

    norm_rope_qk<<<dim3(N_TOK, NH + NKV), 64, 0, stream>>>(qb, kvb, q_norm_w,
                                                           k_norm_w, positions);
    vtrans<<<dim3(32, 8), 256, 0, stream>>>(kvb + 512, vt, 1024);

    wtrans<<<dim3(32, 32, 4), 256, 0, stream>>>(o_proj_w, Wqo, 2048);

    attn_mfma<<<dim3(16, NH), 256, 0, stream>>>(qb, kvb, vt, positions, obf);

    gemm_o<<<dim3(16, 16), 256, 0, stream>>>(obf, Wqo, sort_idx, out);
}

// Round 7
// 357.391 us; speedup vs baseline: 7.4393x; 1.0156x over previous
//
#include <hip/hip_runtime.h>
#include <hip/hip_bf16.h>

#define N_TOK 2048
#define HID   2048
#define NH    32
#define NKV   8
#define HD    64
#define NEXP  4
#define CHUNK (N_TOK / NEXP)   // 512
#define KV_DIM (NKV * HD)      // 512

typedef __attribute__((ext_vector_type(8))) short short8;
typedef __attribute__((ext_vector_type(4))) float float4v;

__device__ inline short f2bf(float f) {
    __hip_bfloat16 h = __float2bfloat16(f);
    return *reinterpret_cast<short*>(&h);
}
__device__ inline float bf2f(short s) {
    __hip_bfloat16 h = *reinterpret_cast<__hip_bfloat16*>(&s);
    return __bfloat162float(h);
}
__device__ __forceinline__ float fast_exp2(float x) {
    float r;
    asm("v_exp_f32 %0, %1" : "=v"(r) : "v"(x));
    return r;
}

// async global->LDS, 16 B per lane; wave-uniform LDS base (m104 caveat).
__device__ __forceinline__ void gld_lds16(const void* g, void* l) {
    __builtin_amdgcn_global_load_lds(
        (const __attribute__((address_space(1))) unsigned int*)g,
        (__attribute__((address_space(3))) unsigned int*)l, 16, 0, 0);
}

// ---------------------------------------------------------------------------
// Shared wtrans tile body: fp32 [k0+64][n0+64] of in (row stride Nw) ->
// bf16 out[n][2048] transposed. Write side vectorized to short8.
// ---------------------------------------------------------------------------
__device__ __forceinline__ void wtrans_tile(
    const float* __restrict__ in, short* __restrict__ out, int Nw,
    int k0, int n0, float (*T)[65], int t)
{
#pragma unroll
    for (int i = 0; i < 16; i++) {
        int idx = t + i * 256, kl = idx >> 6, nl = idx & 63;
        T[kl][nl] = in[(size_t)(k0 + kl) * Nw + n0 + nl];
    }
    __syncthreads();
#pragma unroll
    for (int i = 0; i < 2; i++) {
        int idx = t + i * 256;          // 512 short8 units
        int nl = idx >> 3, k8 = (idx & 7) * 8;
        short8 s;
#pragma unroll
        for (int j = 0; j < 8; j++) s[j] = f2bf(T[k8 + j][nl]);
        *(short8*)&out[(size_t)(n0 + nl) * 2048 + k0 + k8] = s;
    }
}

// ---------------------------------------------------------------------------
// prep1: blocks [0,2048) cvt hidden->bf16 | [2048,6144) wtrans q_proj_w |
//        [6144,6656) wtrans k_w/v_w.
// ---------------------------------------------------------------------------
__global__ __launch_bounds__(256)
void prep1(const float* __restrict__ hidden, const float* __restrict__ qw,
           const float* __restrict__ kw, const float* __restrict__ vw,
           short* __restrict__ Xbf, short* __restrict__ Wq,
           short* __restrict__ Wkv)
{
    __shared__ float T[64][65];
    const int b = blockIdx.x;
    const int t = threadIdx.x;

    if (b < 2048) {                       // cvt
        size_t i = (size_t)b * 256 + t;
        float4 a = ((const float4*)hidden)[i * 2];
        float4 c = ((const float4*)hidden)[i * 2 + 1];
        short8 s;
        s[0] = f2bf(a.x); s[1] = f2bf(a.y); s[2] = f2bf(a.z); s[3] = f2bf(a.w);
        s[4] = f2bf(c.x); s[5] = f2bf(c.y); s[6] = f2bf(c.z); s[7] = f2bf(c.w);
        ((short8*)Xbf)[i] = s;
    } else if (b < 6144) {                // wtrans q (E=4)
        int b2 = b - 2048;
        int k0 = (b2 & 31) * 64, n0 = ((b2 >> 5) & 31) * 64, e = b2 >> 10;
        wtrans_tile(qw + (size_t)e * 2048 * 2048, Wq + (size_t)e * 2048 * 2048,
                    2048, k0, n0, T, t);
    } else {                              // wtrans k/v
        int b3 = b - 6144;
        int k0 = (b3 & 31) * 64, n0 = ((b3 >> 5) & 7) * 64, z = b3 >> 8;
        wtrans_tile(z ? vw : kw, Wkv + (size_t)z * 512 * 2048, 512, k0, n0, T, t);
    }
}

// ---------------------------------------------------------------------------
// prep2: blocks [0,4096) wtrans o_proj_w | [4096,24576) fused q/k RMSNorm+RoPE
//        (4 wave-units/block) | [24576,24832) V transpose.
// ---------------------------------------------------------------------------
__global__ __launch_bounds__(256)
void prep2(const float* __restrict__ ow, short* __restrict__ Wo,
           short* __restrict__ qb, short* __restrict__ kvb,
           const float* __restrict__ qnw, const float* __restrict__ knw,
           const int* __restrict__ positions, short* __restrict__ vt)
{
    __shared__ __align__(16) char smem[64 * 65 * 4];
    const int b = blockIdx.x;
    const int t = threadIdx.x;

    if (b < 4096) {                       // wtrans o (E=4)
        float (*T)[65] = (float(*)[65])smem;
        int k0 = (b & 31) * 64, n0 = ((b >> 5) & 31) * 64, e = b >> 10;
        wtrans_tile(ow + (size_t)e * 2048 * 2048, Wo + (size_t)e * 2048 * 2048,
                    2048, k0, n0, T, t);
    } else if (b < 24576) {               // norm+rope, 4 (row,head) units
        const int lane = t & 63, wave = t >> 6;
        int u = (b - 4096) * 4 + wave;    // u in [0, 81920)
        int row = u / 40, h = u - row * 40;
        short* p;
        const float* w;
        float oscale;
        if (h < NH) { p = qb + (size_t)row * 2048 + h * HD + lane; w = qnw;
                      oscale = 0.125f * 1.44269504f; }
        else        { p = kvb + (size_t)row * 1024 + (h - NH) * HD + lane; w = knw;
                      oscale = 1.0f; }
        float x = bf2f(*p);
        float ss = x * x;
#pragma unroll
        for (int off = 32; off > 0; off >>= 1) ss += __shfl_xor(ss, off, 64);
        float rs = rsqrtf(ss * (1.0f / HD) + 1e-6f);
        float xn = x * rs * w[lane];
        int j = lane & 31;
        float inv_freq = fast_exp2(-(float)j * 0.41524101186f);  // 1e4^(-j/32)
        float fr = (float)positions[row] * inv_freq;
        float c = __cosf(fr), s = __sinf(fr);
        float partner = __shfl_xor(xn, 32, 64);
        float o = (lane < 32) ? (xn * c - partner * s) : (xn * c + partner * s);
        *p = f2bf(o * oscale);
    } else {                              // vtrans
        short (*T)[66] = (short(*)[66])smem;
        int b4 = b - 24576;
        int n0 = (b4 & 31) * 64, h = b4 >> 5;
#pragma unroll
        for (int i = 0; i < 16; i++) {
            int idx = t + i * 256, nl = idx >> 6, dl = idx & 63;
            T[nl][dl] = kvb[(size_t)(n0 + nl) * 1024 + 512 + h * HD + dl];
        }
        __syncthreads();
#pragma unroll
        for (int i = 0; i < 16; i++) {
            int idx = t + i * 256, dl = idx >> 6, nl = idx & 63;
            vt[((size_t)h * HD + dl) * N_TOK + n0 + nl] = T[nl][dl];
        }
    }
}

// ---------------------------------------------------------------------------
// bf16 MFMA GEMM core: 128x128 tile, BK=32, 4 waves, global_load_lds staging.
// (verified R6)
// ---------------------------------------------------------------------------
template <bool OUT_F32>
__device__ __forceinline__ void gemm_core(
    const short* __restrict__ X, const short* __restrict__ Wt,
    const int* __restrict__ sidx, void* __restrict__ OUT,
    int dout, bool routed, int bx, int by,
    short* As, short* Bs, int* ridx)
{
    const int t  = threadIdx.x;
    const int m0 = by * 128;
    const int n0 = bx * 128;

    if (t < 128) ridx[t] = routed ? sidx[m0 + t] : (m0 + t);
    __syncthreads();

    const short* Wb = Wt + (routed ? (size_t)(m0 / CHUNK) * (size_t)dout * 2048 : 0);

    const int seg = (t & 3) * 8;
    const short* ga0 = X  + (size_t)ridx[t >> 2] * 2048 + seg;
    const short* ga1 = X  + (size_t)ridx[64 + (t >> 2)] * 2048 + seg;
    const short* gb0 = Wb + (size_t)(n0 + (t >> 2)) * 2048 + seg;
    const short* gb1 = Wb + (size_t)(n0 + 64 + (t >> 2)) * 2048 + seg;

    const int lane = t & 63;
    const int wave = t >> 6;
    short* lA0 = As + (size_t)(wave * 64) * 8;
    short* lA1 = As + (size_t)(256 + wave * 64) * 8;
    short* lB0 = Bs + (size_t)(wave * 64) * 8;
    short* lB1 = Bs + (size_t)(256 + wave * 64) * 8;

    const int col  = lane & 15;
    const int rowg = lane >> 4;
    const int wm   = (wave >> 1) * 64;
    const int wn   = (wave & 1) * 64;

    int offA[4], offB[4];
#pragma unroll
    for (int i = 0; i < 4; i++) {
        offA[i] = (wm + i * 16 + col) * 32 + rowg * 8;
        offB[i] = (wn + i * 16 + col) * 32 + rowg * 8;
    }

    float4v acc[4][4];
#pragma unroll
    for (int mt = 0; mt < 4; mt++)
#pragma unroll
        for (int nt = 0; nt < 4; nt++) acc[mt][nt] = (float4v){0.f, 0.f, 0.f, 0.f};

    for (int k0 = 0; k0 < 2048; k0 += 32) {
        __syncthreads();
        gld_lds16(ga0 + k0, lA0);
        gld_lds16(ga1 + k0, lA1);
        gld_lds16(gb0 + k0, lB0);
        gld_lds16(gb1 + k0, lB1);
        __syncthreads();

        short8 af[4], bfr[4];
#pragma unroll
        for (int i = 0; i < 4; i++) af[i] = *(const short8*)&As[offA[i]];
#pragma unroll
        for (int i = 0; i < 4; i++) bfr[i] = *(const short8*)&Bs[offB[i]];
#pragma unroll
        for (int mt = 0; mt < 4; mt++)
#pragma unroll
            for (int nt = 0; nt < 4; nt++)
                acc[mt][nt] = __builtin_amdgcn_mfma_f32_16x16x32_bf16(
                    af[mt], bfr[nt], acc[mt][nt], 0, 0, 0);
    }

#pragma unroll
    for (int mt = 0; mt < 4; mt++) {
#pragma unroll
        for (int r = 0; r < 4; r++) {
            int row = ridx[wm + mt * 16 + rowg * 4 + r];
#pragma unroll
            for (int nt = 0; nt < 4; nt++) {
                int colg = n0 + wn + nt * 16 + col;
                float v = acc[mt][nt][r];
                if (OUT_F32) ((float*)OUT)[(size_t)row * dout + colg] = v;
                else         ((short*)OUT)[(size_t)row * dout + colg] = f2bf(v);
            }
        }
    }
}

__global__ __launch_bounds__(256)
void gemm_qkv(const short* __restrict__ X, const short* __restrict__ Wq,
              const short* __restrict__ Wkv, const int* __restrict__ sidx,
              short* __restrict__ qout, short* __restrict__ kvout)
{
    __shared__ __align__(16) short As[128 * 32];
    __shared__ __align__(16) short Bs[128 * 32];
    __shared__ int ridx[128];
    int b = blockIdx.x;
    if (b < 256)
        gemm_core<false>(X, Wq, sidx, qout, 2048, true, b & 15, b >> 4, As, Bs, ridx);
    else {
        b -= 256;
        gemm_core<false>(X, Wkv, nullptr, kvout, 1024, false, b & 7, b >> 3, As, Bs, ridx);
    }
}

__global__ __launch_bounds__(256)
void gemm_o(const short* __restrict__ X, const short* __restrict__ Wt,
            const int* __restrict__ sidx, float* __restrict__ OUT)
{
    __shared__ __align__(16) short As[128 * 32];
    __shared__ __align__(16) short Bs[128 * 32];
    __shared__ int ridx[128];
    gemm_core<true>(X, Wt, sidx, OUT, 2048, true, blockIdx.x, blockIdx.y, As, Bs, ridx);
}

// ---------------------------------------------------------------------------
// MFMA flash attention v3: block = one kv-group x 16 q-rows; 4 waves = the 4
// q-heads sharing K/V staging. Grid 128x8 = 1024 blocks (4/CU, all resident).
// Work-balance map: jj = x&1 ? x>>1 : 127-(x>>1). Fixed-max softmax
// p = exp2(s' - 9*log2e), q pre-scaled by 0.125*log2e (exact; |s|<=8).
// ---------------------------------------------------------------------------
__global__ __launch_bounds__(256)
void attn_mfma(const short* __restrict__ qb, const short* __restrict__ kb,
               const short* __restrict__ vt, const int* __restrict__ positions,
               short* __restrict__ ob)
{
    __shared__ __align__(16) short Ks[64][72];
    __shared__ __align__(16) short Vt[64][72];
    __shared__ __align__(16) short Ps[4][16][72];

    const int x    = blockIdx.x;
    const int jj   = (x & 1) ? (x >> 1) : (127 - (x >> 1));
    const int kvh  = blockIdx.y;
    const int q0   = jj * 16;
    const int t    = threadIdx.x;
    const int lane = t & 63;
    const int wave = t >> 6;
    const int head = kvh * 4 + wave;
    const int rowg = lane >> 4;
    const int col  = lane & 15;

    const int sr = t >> 2;
    const int sc = (t & 3) * 16;
    const float BIAS = 9.0f * 1.44269504f;

    const short* qrow = qb + (size_t)(q0 + col) * HID + head * HD;
    short8 aq0 = *(const short8*)(qrow + rowg * 8);
    short8 aq1 = *(const short8*)(qrow + 32 + rowg * 8);

    int pq[4];
    float l_i[4];
#pragma unroll
    for (int r = 0; r < 4; r++) {
        pq[r] = positions[q0 + rowg * 4 + r];
        l_i[r] = 0.f;
    }
    float4v oacc[4];
#pragma unroll
    for (int n = 0; n < 4; n++) oacc[n] = (float4v){0.f, 0.f, 0.f, 0.f};

    const int nkt = (jj >> 2) + 1;
    for (int kt = 0; kt < nkt; kt++) {
        const int k0 = kt * 64;
        __syncthreads();
        {
            const short* kp = kb + (size_t)(k0 + sr) * 1024 + kvh * HD + sc;
            const short* vp = vt + ((size_t)kvh * HD + sr) * N_TOK + k0 + sc;
            short8 kA = *(const short8*)(kp);
            short8 kB = *(const short8*)(kp + 8);
            short8 vA = *(const short8*)(vp);
            short8 vB = *(const short8*)(vp + 8);
            *(short8*)&Ks[sr][sc]     = kA;
            *(short8*)&Ks[sr][sc + 8] = kB;
            *(short8*)&Vt[sr][sc]     = vA;
            *(short8*)&Vt[sr][sc + 8] = vB;
        }
        __syncthreads();

        float4v c[4];
#pragma unroll
        for (int j = 0; j < 4; j++) {
            short8 blo = *(const short8*)&Ks[j * 16 + col][rowg * 8];
            short8 bhi = *(const short8*)&Ks[j * 16 + col][32 + rowg * 8];
            float4v cc = (float4v){0.f, 0.f, 0.f, 0.f};
            cc = __builtin_amdgcn_mfma_f32_16x16x32_bf16(aq0, blo, cc, 0, 0, 0);
            cc = __builtin_amdgcn_mfma_f32_16x16x32_bf16(aq1, bhi, cc, 0, 0, 0);
            c[j] = cc;
        }

        if (kt == nkt - 1) {              // only the diagonal tile masks
#pragma unroll
            for (int j = 0; j < 4; j++) {
                int pk = positions[k0 + j * 16 + col];
#pragma unroll
                for (int r = 0; r < 4; r++)
                    if (pq[r] < pk) c[j][r] = -1e30f;
            }
        }

#pragma unroll
        for (int j = 0; j < 4; j++)
#pragma unroll
            for (int r = 0; r < 4; r++) {
                float p = fast_exp2(c[j][r] - BIAS);
                l_i[r] += p;
                Ps[wave][rowg * 4 + r][j * 16 + col] = f2bf(p);
            }

        __asm__ volatile("s_waitcnt lgkmcnt(0)" ::: "memory");  // Ps wave-private

        short8 ap0 = *(const short8*)&Ps[wave][col][rowg * 8];
        short8 ap1 = *(const short8*)&Ps[wave][col][32 + rowg * 8];
#pragma unroll
        for (int n = 0; n < 4; n++) {
            short8 blo = *(const short8*)&Vt[n * 16 + col][rowg * 8];
            short8 bhi = *(const short8*)&Vt[n * 16 + col][32 + rowg * 8];
            float4v a2 = oacc[n];
            a2 = __builtin_amdgcn_mfma_f32_16x16x32_bf16(ap0, blo, a2, 0, 0, 0);
            a2 = __builtin_amdgcn_mfma_f32_16x16x32_bf16(ap1, bhi, a2, 0, 0, 0);
            oacc[n] = a2;
        }
    }

#pragma unroll
    for (int r = 0; r < 4; r++) {
#pragma unroll
        for (int off = 1; off < 16; off <<= 1)
            l_i[r] += __shfl_xor(l_i[r], off, 64);
        l_i[r] = 1.f / l_i[r];
    }
#pragma unroll
    for (int n = 0; n < 4; n++)
#pragma unroll
        for (int r = 0; r < 4; r++)
            ob[(size_t)(q0 + rowg * 4 + r) * HID + head * HD + n * 16 + col] =
                f2bf(oacc[n][r] * l_i[r]);
}

// ---------------------------------------------------------------------------
extern "C" void kernel_launch(void* const* d_in, const int* in_sizes, int n_in,
                              void* d_out, int out_size, void* d_ws, size_t ws_size,
                              hipStream_t stream)
{
    (void)in_sizes; (void)n_in; (void)out_size; (void)ws_size;

    const float* hidden    = (const float*)d_in[0];
    const int*   positions = (const int*)  d_in[1];
    const int*   sort_idx  = (const int*)  d_in[2];
    const float* q_proj_w  = (const float*)d_in[3];
    const float* o_proj_w  = (const float*)d_in[4];
    const float* k_w       = (const float*)d_in[5];
    const float* v_w       = (const float*)d_in[6];
    const float* q_norm_w  = (const float*)d_in[7];
    const float* k_norm_w  = (const float*)d_in[8];
    float* out = (float*)d_out;

    const size_t M1 = 1024 * 1024;
    short* Wqo = (short*)d_ws;         // 32 MB (q weights, then o weights)
    short* Wkv = Wqo + 16 * M1;        // 4 MB
    short* Xbf = Wkv + 2 * M1;         // 8 MB (aliased as obf later)
    short* qb  = Xbf + 4 * M1;         // 8 MB
    short* kvb = qb  + 4 * M1;         // 4 MB
    short* vt  = kvb + 2 * M1;         // 2 MB
    short* obf = Xbf;

    prep1<<<6656, 256, 0, stream>>>(hidden, q_proj_w, k_w, v_w, Xbf, Wqo, Wkv);

    gemm_qkv<<<384, 256, 0, stream>>>(Xbf, Wqo, Wkv, sort_idx, qb, kvb);

    prep2<<<24832, 256, 0, stream>>>(o_proj_w, Wqo, qb, kvb, q_norm_w, k_norm_w,
                                     positions, vt);

    attn_mfma<<<dim3(128, 8), 256, 0, stream>>>(qb, kvb, vt, positions, obf);

    gemm_o<<<dim3(16, 16), 256, 0, stream>>>(obf, Wqo, sort_idx, out);
}

// Round 8
// 334.196 us; speedup vs baseline: 7.9556x; 1.0694x over previous
//
#include <hip/hip_runtime.h>
#include <hip/hip_bf16.h>

#define N_TOK 2048
#define HID   2048
#define NH    32
#define NKV   8
#define HD    64
#define NEXP  4
#define CHUNK (N_TOK / NEXP)   // 512
#define KV_DIM (NKV * HD)      // 512

typedef __attribute__((ext_vector_type(8))) short short8;
typedef __attribute__((ext_vector_type(4))) float float4v;

__device__ inline short f2bf(float f) {
    __hip_bfloat16 h = __float2bfloat16(f);
    return *reinterpret_cast<short*>(&h);
}
__device__ inline float bf2f(short s) {
    __hip_bfloat16 h = *reinterpret_cast<__hip_bfloat16*>(&s);
    return __bfloat162float(h);
}
__device__ __forceinline__ float fast_exp2(float x) {
    float r;
    asm("v_exp_f32 %0, %1" : "=v"(r) : "v"(x));
    return r;
}

// async global->LDS, 16 B per lane; wave-uniform LDS base (m104 caveat).
__device__ __forceinline__ void gld_lds16(const void* g, void* l) {
    __builtin_amdgcn_global_load_lds(
        (const __attribute__((address_space(1))) unsigned int*)g,
        (__attribute__((address_space(3))) unsigned int*)l, 16, 0, 0);
}

// ---------------------------------------------------------------------------
// Shared wtrans tile body: fp32 [k0+64][n0+64] of in (row stride Nw) ->
// bf16 out[n][2048] transposed. Write side vectorized to short8.
// ---------------------------------------------------------------------------
__device__ __forceinline__ void wtrans_tile(
    const float* __restrict__ in, short* __restrict__ out, int Nw,
    int k0, int n0, float (*T)[65], int t)
{
#pragma unroll
    for (int i = 0; i < 16; i++) {
        int idx = t + i * 256, kl = idx >> 6, nl = idx & 63;
        T[kl][nl] = in[(size_t)(k0 + kl) * Nw + n0 + nl];
    }
    __syncthreads();
#pragma unroll
    for (int i = 0; i < 2; i++) {
        int idx = t + i * 256;          // 512 short8 units
        int nl = idx >> 3, k8 = (idx & 7) * 8;
        short8 s;
#pragma unroll
        for (int j = 0; j < 8; j++) s[j] = f2bf(T[k8 + j][nl]);
        *(short8*)&out[(size_t)(n0 + nl) * 2048 + k0 + k8] = s;
    }
}

// ---------------------------------------------------------------------------
// prep1: blocks [0,2048) cvt hidden->bf16 | [2048,6144) wtrans q_proj_w |
//        [6144,6656) wtrans k_w/v_w.
// ---------------------------------------------------------------------------
__global__ __launch_bounds__(256)
void prep1(const float* __restrict__ hidden, const float* __restrict__ qw,
           const float* __restrict__ kw, const float* __restrict__ vw,
           short* __restrict__ Xbf, short* __restrict__ Wq,
           short* __restrict__ Wkv)
{
    __shared__ float T[64][65];
    const int b = blockIdx.x;
    const int t = threadIdx.x;

    if (b < 2048) {                       // cvt
        size_t i = (size_t)b * 256 + t;
        float4 a = ((const float4*)hidden)[i * 2];
        float4 c = ((const float4*)hidden)[i * 2 + 1];
        short8 s;
        s[0] = f2bf(a.x); s[1] = f2bf(a.y); s[2] = f2bf(a.z); s[3] = f2bf(a.w);
        s[4] = f2bf(c.x); s[5] = f2bf(c.y); s[6] = f2bf(c.z); s[7] = f2bf(c.w);
        ((short8*)Xbf)[i] = s;
    } else if (b < 6144) {                // wtrans q (E=4)
        int b2 = b - 2048;
        int k0 = (b2 & 31) * 64, n0 = ((b2 >> 5) & 31) * 64, e = b2 >> 10;
        wtrans_tile(qw + (size_t)e * 2048 * 2048, Wq + (size_t)e * 2048 * 2048,
                    2048, k0, n0, T, t);
    } else {                              // wtrans k/v
        int b3 = b - 6144;
        int k0 = (b3 & 31) * 64, n0 = ((b3 >> 5) & 7) * 64, z = b3 >> 8;
        wtrans_tile(z ? vw : kw, Wkv + (size_t)z * 512 * 2048, 512, k0, n0, T, t);
    }
}

// ---------------------------------------------------------------------------
// prep2: blocks [0,4096) wtrans o_proj_w | [4096,24576) fused q/k RMSNorm+RoPE
//        (4 wave-units/block) | [24576,24832) V transpose.
// ---------------------------------------------------------------------------
__global__ __launch_bounds__(256)
void prep2(const float* __restrict__ ow, short* __restrict__ Wo,
           short* __restrict__ qb, short* __restrict__ kvb,
           const float* __restrict__ qnw, const float* __restrict__ knw,
           const int* __restrict__ positions, short* __restrict__ vt)
{
    __shared__ __align__(16) char smem[64 * 65 * 4];
    const int b = blockIdx.x;
    const int t = threadIdx.x;

    if (b < 4096) {                       // wtrans o (E=4)
        float (*T)[65] = (float(*)[65])smem;
        int k0 = (b & 31) * 64, n0 = ((b >> 5) & 31) * 64, e = b >> 10;
        wtrans_tile(ow + (size_t)e * 2048 * 2048, Wo + (size_t)e * 2048 * 2048,
                    2048, k0, n0, T, t);
    } else if (b < 24576) {               // norm+rope, 4 (row,head) units
        const int lane = t & 63, wave = t >> 6;
        int u = (b - 4096) * 4 + wave;    // u in [0, 81920)
        int row = u / 40, h = u - row * 40;
        short* p;
        const float* w;
        float oscale;
        if (h < NH) { p = qb + (size_t)row * 2048 + h * HD + lane; w = qnw;
                      oscale = 0.125f * 1.44269504f; }
        else        { p = kvb + (size_t)row * 1024 + (h - NH) * HD + lane; w = knw;
                      oscale = 1.0f; }
        float x = bf2f(*p);
        float ss = x * x;
#pragma unroll
        for (int off = 32; off > 0; off >>= 1) ss += __shfl_xor(ss, off, 64);
        float rs = rsqrtf(ss * (1.0f / HD) + 1e-6f);
        float xn = x * rs * w[lane];
        int j = lane & 31;
        float inv_freq = fast_exp2(-(float)j * 0.41524101186f);  // 1e4^(-j/32)
        float fr = (float)positions[row] * inv_freq;
        float c = __cosf(fr), s = __sinf(fr);
        float partner = __shfl_xor(xn, 32, 64);
        float o = (lane < 32) ? (xn * c - partner * s) : (xn * c + partner * s);
        *p = f2bf(o * oscale);
    } else {                              // vtrans
        short (*T)[66] = (short(*)[66])smem;
        int b4 = b - 24576;
        int n0 = (b4 & 31) * 64, h = b4 >> 5;
#pragma unroll
        for (int i = 0; i < 16; i++) {
            int idx = t + i * 256, nl = idx >> 6, dl = idx & 63;
            T[nl][dl] = kvb[(size_t)(n0 + nl) * 1024 + 512 + h * HD + dl];
        }
        __syncthreads();
#pragma unroll
        for (int i = 0; i < 16; i++) {
            int idx = t + i * 256, dl = idx >> 6, nl = idx & 63;
            vt[((size_t)h * HD + dl) * N_TOK + n0 + nl] = T[nl][dl];
        }
    }
}

// ---------------------------------------------------------------------------
// bf16 MFMA GEMM core: 128x128 tile, BK=32, 4 waves, global_load_lds staging,
// single-barrier LDS DOUBLE-BUFFER: prefetch tile k+1 issued before compute
// of tile k; s_waitcnt vmcnt(0) lands after compute (DMA latency hidden).
// Raw s_barrier (no compiler-forced drain before it).
// ---------------------------------------------------------------------------
template <bool OUT_F32>
__device__ __forceinline__ void gemm_core(
    const short* __restrict__ X, const short* __restrict__ Wt,
    const int* __restrict__ sidx, void* __restrict__ OUT,
    int dout, bool routed, int bx, int by,
    short* As0, short* Bs0, short* As1, short* Bs1, int* ridx)
{
    const int t  = threadIdx.x;
    const int m0 = by * 128;
    const int n0 = bx * 128;

    if (t < 128) ridx[t] = routed ? sidx[m0 + t] : (m0 + t);
    __syncthreads();

    const short* Wb = Wt + (routed ? (size_t)(m0 / CHUNK) * (size_t)dout * 2048 : 0);

    const int seg = (t & 3) * 8;
    const short* ga0 = X  + (size_t)ridx[t >> 2] * 2048 + seg;
    const short* ga1 = X  + (size_t)ridx[64 + (t >> 2)] * 2048 + seg;
    const short* gb0 = Wb + (size_t)(n0 + (t >> 2)) * 2048 + seg;
    const short* gb1 = Wb + (size_t)(n0 + 64 + (t >> 2)) * 2048 + seg;

    const int lane = t & 63;
    const int wave = t >> 6;
    const int wl   = wave * 64 * 8;        // wave-uniform staging base (shorts)
    const int col  = lane & 15;
    const int rowg = lane >> 4;
    const int wm   = (wave >> 1) * 64;
    const int wn   = (wave & 1) * 64;

    int offA[4], offB[4];
#pragma unroll
    for (int i = 0; i < 4; i++) {
        offA[i] = (wm + i * 16 + col) * 32 + rowg * 8;
        offB[i] = (wn + i * 16 + col) * 32 + rowg * 8;
    }

    float4v acc[4][4];
#pragma unroll
    for (int mt = 0; mt < 4; mt++)
#pragma unroll
        for (int nt = 0; nt < 4; nt++) acc[mt][nt] = (float4v){0.f, 0.f, 0.f, 0.f};

    auto stage = [&](int k0, short* A, short* B) {
        gld_lds16(ga0 + k0, A + wl);
        gld_lds16(ga1 + k0, A + 256 * 8 + wl);
        gld_lds16(gb0 + k0, B + wl);
        gld_lds16(gb1 + k0, B + 256 * 8 + wl);
    };
    auto compute = [&](const short* A, const short* B) {
        short8 af[4], bfr[4];
#pragma unroll
        for (int i = 0; i < 4; i++) af[i] = *(const short8*)&A[offA[i]];
#pragma unroll
        for (int i = 0; i < 4; i++) bfr[i] = *(const short8*)&B[offB[i]];
#pragma unroll
        for (int mt = 0; mt < 4; mt++)
#pragma unroll
            for (int nt = 0; nt < 4; nt++)
                acc[mt][nt] = __builtin_amdgcn_mfma_f32_16x16x32_bf16(
                    af[mt], bfr[nt], acc[mt][nt], 0, 0, 0);
    };

    stage(0, As0, Bs0);
    asm volatile("s_waitcnt vmcnt(0)" ::: "memory");
    __builtin_amdgcn_s_barrier();

    for (int k0 = 0; k0 < 2048; k0 += 64) {
        stage(k0 + 32, As1, Bs1);                 // prefetch (always in-range)
        compute(As0, Bs0);
        asm volatile("s_waitcnt vmcnt(0)" ::: "memory");  // prefetch done (hidden)
        __builtin_amdgcn_s_barrier();             // all waves: reads done, buf1 ready

        if (k0 + 64 < 2048) stage(k0 + 64, As0, Bs0);
        compute(As1, Bs1);
        asm volatile("s_waitcnt vmcnt(0)" ::: "memory");
        __builtin_amdgcn_s_barrier();
    }

#pragma unroll
    for (int mt = 0; mt < 4; mt++) {
#pragma unroll
        for (int r = 0; r < 4; r++) {
            int row = ridx[wm + mt * 16 + rowg * 4 + r];
#pragma unroll
            for (int nt = 0; nt < 4; nt++) {
                int colg = n0 + wn + nt * 16 + col;
                float v = acc[mt][nt][r];
                if (OUT_F32) ((float*)OUT)[(size_t)row * dout + colg] = v;
                else         ((short*)OUT)[(size_t)row * dout + colg] = f2bf(v);
            }
        }
    }
}

__global__ __launch_bounds__(256)
void gemm_qkv(const short* __restrict__ X, const short* __restrict__ Wq,
              const short* __restrict__ Wkv, const int* __restrict__ sidx,
              short* __restrict__ qout, short* __restrict__ kvout)
{
    __shared__ __align__(16) short As0[128 * 32], Bs0[128 * 32];
    __shared__ __align__(16) short As1[128 * 32], Bs1[128 * 32];
    __shared__ int ridx[128];
    int b = blockIdx.x;
    if (b < 256)
        gemm_core<false>(X, Wq, sidx, qout, 2048, true, b & 15, b >> 4,
                         As0, Bs0, As1, Bs1, ridx);
    else {
        b -= 256;
        gemm_core<false>(X, Wkv, nullptr, kvout, 1024, false, b & 7, b >> 3,
                         As0, Bs0, As1, Bs1, ridx);
    }
}

__global__ __launch_bounds__(256)
void gemm_o(const short* __restrict__ X, const short* __restrict__ Wt,
            const int* __restrict__ sidx, float* __restrict__ OUT)
{
    __shared__ __align__(16) short As0[128 * 32], Bs0[128 * 32];
    __shared__ __align__(16) short As1[128 * 32], Bs1[128 * 32];
    __shared__ int ridx[128];
    gemm_core<true>(X, Wt, sidx, OUT, 2048, true, blockIdx.x, blockIdx.y,
                    As0, Bs0, As1, Bs1, ridx);
}

// ---------------------------------------------------------------------------
// MFMA flash attention (R5 structure, verified): K-tile 64, fixed-max softmax
// p = exp2(s' - 9*log2e) (exact: q pre-scaled by 0.125*log2e, |s|<=8 after
// RMSNorm+RoPE), paired q-tiles (31-x heavy, then x) -> uniform 33 tiles per
// block, grid 16 x 32 heads = 512 blocks.
// ---------------------------------------------------------------------------
__global__ __launch_bounds__(256)
void attn_mfma(const short* __restrict__ qb, const short* __restrict__ kb,
               const short* __restrict__ vt, const int* __restrict__ positions,
               short* __restrict__ ob)
{
    __shared__ __align__(16) short Ks[64][72];
    __shared__ __align__(16) short Vt[64][72];
    __shared__ __align__(16) short Ps[4][16][72];

    const int head = blockIdx.y;
    const int kvh  = head >> 2;
    const int t    = threadIdx.x;
    const int lane = t & 63;
    const int wave = t >> 6;
    const int rowg = lane >> 4;
    const int col  = lane & 15;

    const int sr = t >> 2;
    const int sc = (t & 3) * 16;
    const float BIAS = 9.0f * 1.44269504f;

#pragma unroll
    for (int pass = 0; pass < 2; pass++) {
        const int qt = pass == 0 ? (31 - (int)blockIdx.x) : (int)blockIdx.x;
        const int q0 = qt * 64;
        const int m0 = q0 + wave * 16;

        const short* qrow = qb + (size_t)(m0 + col) * HID + head * HD;
        short8 aq0 = *(const short8*)(qrow + rowg * 8);
        short8 aq1 = *(const short8*)(qrow + 32 + rowg * 8);

        int pq[4];
        float l_i[4];
#pragma unroll
        for (int r = 0; r < 4; r++) {
            pq[r] = positions[m0 + rowg * 4 + r];
            l_i[r] = 0.f;
        }
        float4v oacc[4];
#pragma unroll
        for (int n = 0; n < 4; n++) oacc[n] = (float4v){0.f, 0.f, 0.f, 0.f};

        const int nkt = qt + 1;
        for (int kt = 0; kt < nkt; kt++) {
            const int k0 = kt * 64;
            __syncthreads();
            {
                const short* kp = kb + (size_t)(k0 + sr) * 1024 + kvh * HD + sc;
                const short* vp = vt + ((size_t)kvh * HD + sr) * N_TOK + k0 + sc;
                short8 kA = *(const short8*)(kp);
                short8 kB = *(const short8*)(kp + 8);
                short8 vA = *(const short8*)(vp);
                short8 vB = *(const short8*)(vp + 8);
                *(short8*)&Ks[sr][sc]     = kA;
                *(short8*)&Ks[sr][sc + 8] = kB;
                *(short8*)&Vt[sr][sc]     = vA;
                *(short8*)&Vt[sr][sc + 8] = vB;
            }
            __syncthreads();

            float4v c[4];
#pragma unroll
            for (int j = 0; j < 4; j++) {
                short8 blo = *(const short8*)&Ks[j * 16 + col][rowg * 8];
                short8 bhi = *(const short8*)&Ks[j * 16 + col][32 + rowg * 8];
                float4v cc = (float4v){0.f, 0.f, 0.f, 0.f};
                cc = __builtin_amdgcn_mfma_f32_16x16x32_bf16(aq0, blo, cc, 0, 0, 0);
                cc = __builtin_amdgcn_mfma_f32_16x16x32_bf16(aq1, bhi, cc, 0, 0, 0);
                c[j] = cc;
            }

            if (kt == qt) {               // only the diagonal tile masks
#pragma unroll
                for (int j = 0; j < 4; j++) {
                    int pk = positions[k0 + j * 16 + col];
#pragma unroll
                    for (int r = 0; r < 4; r++)
                        if (pq[r] < pk) c[j][r] = -1e30f;
                }
            }

#pragma unroll
            for (int j = 0; j < 4; j++)
#pragma unroll
                for (int r = 0; r < 4; r++) {
                    float p = fast_exp2(c[j][r] - BIAS);
                    l_i[r] += p;
                    Ps[wave][rowg * 4 + r][j * 16 + col] = f2bf(p);
                }

            __asm__ volatile("s_waitcnt lgkmcnt(0)" ::: "memory");  // Ps wave-private

            short8 ap0 = *(const short8*)&Ps[wave][col][rowg * 8];
            short8 ap1 = *(const short8*)&Ps[wave][col][32 + rowg * 8];
#pragma unroll
            for (int n = 0; n < 4; n++) {
                short8 blo = *(const short8*)&Vt[n * 16 + col][rowg * 8];
                short8 bhi = *(const short8*)&Vt[n * 16 + col][32 + rowg * 8];
                float4v a2 = oacc[n];
                a2 = __builtin_amdgcn_mfma_f32_16x16x32_bf16(ap0, blo, a2, 0, 0, 0);
                a2 = __builtin_amdgcn_mfma_f32_16x16x32_bf16(ap1, bhi, a2, 0, 0, 0);
                oacc[n] = a2;
            }
        }

#pragma unroll
        for (int r = 0; r < 4; r++) {
#pragma unroll
            for (int off = 1; off < 16; off <<= 1)
                l_i[r] += __shfl_xor(l_i[r], off, 64);
            l_i[r] = 1.f / l_i[r];
        }
#pragma unroll
        for (int n = 0; n < 4; n++)
#pragma unroll
            for (int r = 0; r < 4; r++)
                ob[(size_t)(m0 + rowg * 4 + r) * HID + head * HD + n * 16 + col] =
                    f2bf(oacc[n][r] * l_i[r]);
    }
}

// ---------------------------------------------------------------------------
extern "C" void kernel_launch(void* const* d_in, const int* in_sizes, int n_in,
                              void* d_out, int out_size, void* d_ws, size_t ws_size,
                              hipStream_t stream)
{
    (void)in_sizes; (void)n_in; (void)out_size; (void)ws_size;

    const float* hidden    = (const float*)d_in[0];
    const int*   positions = (const int*)  d_in[1];
    const int*   sort_idx  = (const int*)  d_in[2];
    const float* q_proj_w  = (const float*)d_in[3];
    const float* o_proj_w  = (const float*)d_in[4];
    const float* k_w       = (const float*)d_in[5];
    const float* v_w       = (const float*)d_in[6];
    const float* q_norm_w  = (const float*)d_in[7];
    const float* k_norm_w  = (const float*)d_in[8];
    float* out = (float*)d_out;

    const size_t M1 = 1024 * 1024;
    short* Wqo = (short*)d_ws;         // 32 MB (q weights, then o weights)
    short* Wkv = Wqo + 16 * M1;        // 4 MB
    short* Xbf = Wkv + 2 * M1;         // 8 MB (aliased as obf later)
    short* qb  = Xbf + 4 * M1;         // 8 MB
    short* kvb = qb  + 4 * M1;         // 4 MB
    short* vt  = kvb + 2 * M1;         // 2 MB
    short* obf = Xbf;

    prep1<<<6656, 256, 0, stream>>>(hidden, q_proj_w, k_w, v_w, Xbf, Wqo, Wkv);

    gemm_qkv<<<384, 256, 0, stream>>>(Xbf, Wqo, Wkv, sort_idx, qb, kvb);

    prep2<<<24832, 256, 0, stream>>>(o_proj_w, Wqo, qb, kvb, q_norm_w, k_norm_w,
                                     positions, vt);

    attn_mfma<<<dim3(16, NH), 256, 0, stream>>>(qb, kvb, vt, positions, obf);

    gemm_o<<<dim3(16, 16), 256, 0, stream>>>(obf, Wqo, sort_idx, out);
}

// Round 9
// 298.816 us; speedup vs baseline: 8.8976x; 1.1184x over previous
//
#include <hip/hip_runtime.h>
#include <hip/hip_bf16.h>

#define N_TOK 2048
#define HID   2048
#define NH    32
#define NKV   8
#define HD    64
#define NEXP  4
#define CHUNK (N_TOK / NEXP)   // 512

typedef __attribute__((ext_vector_type(8))) short short8;
typedef __attribute__((ext_vector_type(4))) short short4v;
typedef __attribute__((ext_vector_type(4))) float float4v;

#define QSCALE (0.125f * 1.44269504f)   // softmax scale * log2e (exp2 domain)
#define RLOG   0.41524101186f           // log2(1e4)/32

__device__ inline short f2bf(float f) {
    __hip_bfloat16 h = __float2bfloat16(f);
    return *reinterpret_cast<short*>(&h);
}
__device__ inline float bf2f(short s) {
    __hip_bfloat16 h = *reinterpret_cast<__hip_bfloat16*>(&s);
    return __bfloat162float(h);
}
__device__ __forceinline__ float fast_exp2(float x) {
    float r;
    asm("v_exp_f32 %0, %1" : "=v"(r) : "v"(x));
    return r;
}

// async global->LDS, 16 B per lane; wave-uniform LDS base (m104 caveat).
__device__ __forceinline__ void gld_lds16(const void* g, void* l) {
    __builtin_amdgcn_global_load_lds(
        (const __attribute__((address_space(1))) unsigned int*)g,
        (__attribute__((address_space(3))) unsigned int*)l, 16, 0, 0);
}

// ---------------------------------------------------------------------------
// wtrans tile body: fp32 [k0+64)x[n0+64) of in (row stride Nw) -> bf16
// out[n][2048] transposed; write side short8-vectorized.
// ---------------------------------------------------------------------------
__device__ __forceinline__ void wtrans_tile(
    const float* __restrict__ in, short* __restrict__ out, int Nw,
    int k0, int n0, float (*T)[65], int t)
{
#pragma unroll
    for (int i = 0; i < 16; i++) {
        int idx = t + i * 256, kl = idx >> 6, nl = idx & 63;
        T[kl][nl] = in[(size_t)(k0 + kl) * Nw + n0 + nl];
    }
    __syncthreads();
#pragma unroll
    for (int i = 0; i < 2; i++) {
        int idx = t + i * 256;
        int nl = idx >> 3, k8 = (idx & 7) * 8;
        short8 s;
#pragma unroll
        for (int j = 0; j < 8; j++) s[j] = f2bf(T[k8 + j][nl]);
        *(short8*)&out[(size_t)(n0 + nl) * 2048 + k0 + k8] = s;
    }
}

// ---------------------------------------------------------------------------
// prep1: [0,2048) cvt hidden->bf16 | [2048,6144) wtrans q_proj_w |
//        [6144,6656) wtrans k_w/v_w.
// ---------------------------------------------------------------------------
__global__ __launch_bounds__(256)
void prep1(const float* __restrict__ hidden, const float* __restrict__ qw,
           const float* __restrict__ kw, const float* __restrict__ vw,
           short* __restrict__ Xbf, short* __restrict__ Wq,
           short* __restrict__ Wkv)
{
    __shared__ float T[64][65];
    const int b = blockIdx.x;
    const int t = threadIdx.x;

    if (b < 2048) {
        size_t i = (size_t)b * 256 + t;
        float4 a = ((const float4*)hidden)[i * 2];
        float4 c = ((const float4*)hidden)[i * 2 + 1];
        short8 s;
        s[0] = f2bf(a.x); s[1] = f2bf(a.y); s[2] = f2bf(a.z); s[3] = f2bf(a.w);
        s[4] = f2bf(c.x); s[5] = f2bf(c.y); s[6] = f2bf(c.z); s[7] = f2bf(c.w);
        ((short8*)Xbf)[i] = s;
    } else if (b < 6144) {
        int b2 = b - 2048;
        int k0 = (b2 & 31) * 64, n0 = ((b2 >> 5) & 31) * 64, e = b2 >> 10;
        wtrans_tile(qw + (size_t)e * 2048 * 2048, Wq + (size_t)e * 2048 * 2048,
                    2048, k0, n0, T, t);
    } else {
        int b3 = b - 6144;
        int k0 = (b3 & 31) * 64, n0 = ((b3 >> 5) & 7) * 64, z = b3 >> 8;
        wtrans_tile(z ? vw : kw, Wkv + (size_t)z * 512 * 2048, 512, k0, n0, T, t);
    }
}

// ---------------------------------------------------------------------------
// bf16 MFMA GEMM core, 128x128 tile, BK=32, 4 waves, global_load_lds dbuf
// staging (R8 verified). Fused epilogues:
//   EPI 0: fp32 store (o-proj)
//   EPI 1: q RMSNorm + RoPE + QSCALE, bf16 store to qb (stride 2048)
//   EPI 2: kv GEMM -- k cols (n<512): RMSNorm+RoPE -> kb (stride 512);
//          v cols: transposed bf16 store to vt[d][token] (stride 2048)
// RMS/RoPE are in-register: wave's 64-col tile == one head; partner d^32 is
// register nt^2 in the same lane; RMS sum = per-lane Σ_nt + 16-lane shfl.
// ---------------------------------------------------------------------------
template <int EPI>
__device__ __forceinline__ void gemm_core(
    const short* __restrict__ X, const short* __restrict__ Wt,
    const int* __restrict__ sidx, void* __restrict__ OUT,
    int dout, bool routed, int bx, int by,
    const int* __restrict__ positions, const float* __restrict__ nw,
    short* __restrict__ vt,
    short* As0, short* Bs0, short* As1, short* Bs1, int* ridx)
{
    const int t  = threadIdx.x;
    const int m0 = by * 128;
    const int n0 = bx * 128;

    if (t < 128) ridx[t] = routed ? sidx[m0 + t] : (m0 + t);
    __syncthreads();

    const short* Wb = Wt + (routed ? (size_t)(m0 / CHUNK) * (size_t)dout * 2048 : 0);

    const int seg = (t & 3) * 8;
    const short* ga0 = X  + (size_t)ridx[t >> 2] * 2048 + seg;
    const short* ga1 = X  + (size_t)ridx[64 + (t >> 2)] * 2048 + seg;
    const short* gb0 = Wb + (size_t)(n0 + (t >> 2)) * 2048 + seg;
    const short* gb1 = Wb + (size_t)(n0 + 64 + (t >> 2)) * 2048 + seg;

    const int lane = t & 63;
    const int wave = t >> 6;
    const int wl   = wave * 64 * 8;
    const int col  = lane & 15;
    const int rowg = lane >> 4;
    const int wm   = (wave >> 1) * 64;
    const int wn   = (wave & 1) * 64;

    int offA[4], offB[4];
#pragma unroll
    for (int i = 0; i < 4; i++) {
        offA[i] = (wm + i * 16 + col) * 32 + rowg * 8;
        offB[i] = (wn + i * 16 + col) * 32 + rowg * 8;
    }

    float4v acc[4][4];
#pragma unroll
    for (int mt = 0; mt < 4; mt++)
#pragma unroll
        for (int nt = 0; nt < 4; nt++) acc[mt][nt] = (float4v){0.f, 0.f, 0.f, 0.f};

    auto stage = [&](int k0, short* A, short* B) {
        gld_lds16(ga0 + k0, A + wl);
        gld_lds16(ga1 + k0, A + 256 * 8 + wl);
        gld_lds16(gb0 + k0, B + wl);
        gld_lds16(gb1 + k0, B + 256 * 8 + wl);
    };
    auto compute = [&](const short* A, const short* B) {
        short8 af[4], bfr[4];
#pragma unroll
        for (int i = 0; i < 4; i++) af[i] = *(const short8*)&A[offA[i]];
#pragma unroll
        for (int i = 0; i < 4; i++) bfr[i] = *(const short8*)&B[offB[i]];
#pragma unroll
        for (int mt = 0; mt < 4; mt++)
#pragma unroll
            for (int nt = 0; nt < 4; nt++)
                acc[mt][nt] = __builtin_amdgcn_mfma_f32_16x16x32_bf16(
                    af[mt], bfr[nt], acc[mt][nt], 0, 0, 0);
    };

    stage(0, As0, Bs0);
    asm volatile("s_waitcnt vmcnt(0)" ::: "memory");
    __builtin_amdgcn_s_barrier();

    for (int k0 = 0; k0 < 2048; k0 += 64) {
        stage(k0 + 32, As1, Bs1);
        compute(As0, Bs0);
        asm volatile("s_waitcnt vmcnt(0)" ::: "memory");
        __builtin_amdgcn_s_barrier();

        if (k0 + 64 < 2048) stage(k0 + 64, As0, Bs0);
        compute(As1, Bs1);
        asm volatile("s_waitcnt vmcnt(0)" ::: "memory");
        __builtin_amdgcn_s_barrier();
    }

    if (EPI == 0) {
#pragma unroll
        for (int mt = 0; mt < 4; mt++)
#pragma unroll
            for (int r = 0; r < 4; r++) {
                int row = ridx[wm + mt * 16 + rowg * 4 + r];
#pragma unroll
                for (int nt = 0; nt < 4; nt++)
                    ((float*)OUT)[(size_t)row * dout + n0 + wn + nt * 16 + col] =
                        acc[mt][nt][r];
            }
        return;
    }

    const bool is_v = (EPI == 2) && (n0 + wn >= 512);

    if (is_v) {   // transposed bf16 store: vt[d][token], 4 tokens per store
#pragma unroll
        for (int mt = 0; mt < 4; mt++) {
            int rowb = m0 + wm + mt * 16 + rowg * 4;   // identity rows (kv)
#pragma unroll
            for (int nt = 0; nt < 4; nt++) {
                int d = n0 + wn + nt * 16 + col - 512;
                short4v sv;
#pragma unroll
                for (int r = 0; r < 4; r++) sv[r] = f2bf(acc[mt][nt][r]);
                *(short4v*)&vt[(size_t)d * N_TOK + rowb] = sv;
            }
        }
        return;
    }

    // q (EPI 1) or k (EPI 2, n<512): RMSNorm + NeoX RoPE, bf16 store
    {
        const int   h     = (n0 + wn) >> 6;
        const float oscl  = (EPI == 1) ? QSCALE : 1.0f;
        const int   ldo   = (EPI == 1) ? 2048 : 512;
        short* ob = (short*)OUT;
        float invf0 = fast_exp2(-(float)col * RLOG);          // j = col
        float invf1 = fast_exp2(-(float)(16 + col) * RLOG);   // j = 16+col
        float wv[4];
#pragma unroll
        for (int nt = 0; nt < 4; nt++) wv[nt] = nw[nt * 16 + col];

#pragma unroll
        for (int mt = 0; mt < 4; mt++)
#pragma unroll
            for (int r = 0; r < 4; r++) {
                int row = ridx[wm + mt * 16 + rowg * 4 + r];
                float x0 = acc[mt][0][r], x1 = acc[mt][1][r];
                float x2 = acc[mt][2][r], x3 = acc[mt][3][r];
                float ss = x0 * x0 + x1 * x1 + x2 * x2 + x3 * x3;
#pragma unroll
                for (int off = 1; off < 16; off <<= 1)
                    ss += __shfl_xor(ss, off, 64);
                float rs = rsqrtf(ss * (1.0f / HD) + 1e-6f);
                x0 *= rs * wv[0]; x1 *= rs * wv[1];
                x2 *= rs * wv[2]; x3 *= rs * wv[3];
                float pos = (float)positions[row];
                float fr0 = pos * invf0, fr1 = pos * invf1;
                float c0 = __cosf(fr0), s0 = __sinf(fr0);
                float c1 = __cosf(fr1), s1 = __sinf(fr1);
                float o0 = x0 * c0 - x2 * s0;
                float o1 = x1 * c1 - x3 * s1;
                float o2 = x2 * c0 + x0 * s0;
                float o3 = x3 * c1 + x1 * s1;
                size_t base = (size_t)row * ldo + h * 64 + col;
                ob[base]      = f2bf(o0 * oscl);
                ob[base + 16] = f2bf(o1 * oscl);
                ob[base + 32] = f2bf(o2 * oscl);
                ob[base + 48] = f2bf(o3 * oscl);
            }
    }
}

// fused q-proj (256 blocks, routed, EPI1) + kv-proj (128 blocks, EPI2)
__global__ __launch_bounds__(256)
void gemm_qkv(const short* __restrict__ X, const short* __restrict__ Wq,
              const short* __restrict__ Wkv, const int* __restrict__ sidx,
              short* __restrict__ qb, short* __restrict__ kb,
              short* __restrict__ vt, const int* __restrict__ positions,
              const float* __restrict__ qnw, const float* __restrict__ knw)
{
    __shared__ __align__(16) short As0[128 * 32], Bs0[128 * 32];
    __shared__ __align__(16) short As1[128 * 32], Bs1[128 * 32];
    __shared__ int ridx[128];
    int b = blockIdx.x;
    if (b < 256)
        gemm_core<1>(X, Wq, sidx, qb, 2048, true, b & 15, b >> 4,
                     positions, qnw, nullptr, As0, Bs0, As1, Bs1, ridx);
    else {
        b -= 256;
        gemm_core<2>(X, Wkv, nullptr, kb, 1024, false, b & 7, b >> 3,
                     positions, knw, vt, As0, Bs0, As1, Bs1, ridx);
    }
}

__global__ __launch_bounds__(256)
void gemm_o(const short* __restrict__ X, const short* __restrict__ Wt,
            const int* __restrict__ sidx, float* __restrict__ OUT)
{
    __shared__ __align__(16) short As0[128 * 32], Bs0[128 * 32];
    __shared__ __align__(16) short As1[128 * 32], Bs1[128 * 32];
    __shared__ int ridx[128];
    gemm_core<0>(X, Wt, sidx, OUT, 2048, true, blockIdx.x, blockIdx.y,
                 nullptr, nullptr, nullptr, As0, Bs0, As1, Bs1, ridx);
}

// ---------------------------------------------------------------------------
// D3: blocks [0,512) MFMA flash attention (R8-verified structure + next-tile
// register prefetch) | [512,4608) wtrans o_proj_w into Wo (free to overlap:
// attn doesn't touch Wo; gemm_o is a later dispatch).
// ---------------------------------------------------------------------------
__global__ __launch_bounds__(256)
void attn_plus(const short* __restrict__ qb, const short* __restrict__ kb,
               const short* __restrict__ vt, const int* __restrict__ positions,
               short* __restrict__ ob,
               const float* __restrict__ ow, short* __restrict__ Wo)
{
    __shared__ __align__(16) char smem[27648];
    const int b = blockIdx.x;
    const int t = threadIdx.x;

    if (b >= 512) {   // o-weight transpose
        float (*T)[65] = (float(*)[65])smem;
        int b2 = b - 512;
        int k0 = (b2 & 31) * 64, n0 = ((b2 >> 5) & 31) * 64, e = b2 >> 10;
        wtrans_tile(ow + (size_t)e * 2048 * 2048, Wo + (size_t)e * 2048 * 2048,
                    2048, k0, n0, T, t);
        return;
    }

    short (*Ks)[72] = (short(*)[72])smem;                      // 64x72
    short (*Vt)[72] = (short(*)[72])(smem + 64 * 72 * 2);      // 64x72
    short (*Ps)[72] = (short(*)[72])(smem + 2 * 64 * 72 * 2);  // [4*16][72]

    const int head = b >> 4;
    const int kvh  = head >> 2;
    const int lane = t & 63;
    const int wave = t >> 6;
    const int rowg = lane >> 4;
    const int col  = lane & 15;

    const int sr = t >> 2;
    const int sc = (t & 3) * 16;
    const float BIAS = 9.0f * 1.44269504f;

#pragma unroll
    for (int pass = 0; pass < 2; pass++) {
        const int qt = pass == 0 ? (31 - (b & 15)) : (b & 15);
        const int q0 = qt * 64;
        const int m0 = q0 + wave * 16;

        const short* qrow = qb + (size_t)(m0 + col) * HID + head * HD;
        short8 aq0 = *(const short8*)(qrow + rowg * 8);
        short8 aq1 = *(const short8*)(qrow + 32 + rowg * 8);

        int pq[4];
        float l_i[4];
#pragma unroll
        for (int r = 0; r < 4; r++) {
            pq[r] = positions[m0 + rowg * 4 + r];
            l_i[r] = 0.f;
        }
        float4v oacc[4];
#pragma unroll
        for (int n = 0; n < 4; n++) oacc[n] = (float4v){0.f, 0.f, 0.f, 0.f};

        const short* kpb = kb + (size_t)sr * 512 + kvh * HD + sc;
        const short* vpb = vt + ((size_t)kvh * HD + sr) * N_TOK + sc;

        const int nkt = qt + 1;
        short8 kA, kB, vA, vB;
        {   // preload tile 0
            kA = *(const short8*)(kpb);
            kB = *(const short8*)(kpb + 8);
            vA = *(const short8*)(vpb);
            vB = *(const short8*)(vpb + 8);
        }

        for (int kt = 0; kt < nkt; kt++) {
            __syncthreads();              // prev tile's LDS reads done
            *(short8*)&Ks[sr][sc]     = kA;
            *(short8*)&Ks[sr][sc + 8] = kB;
            *(short8*)&Vt[sr][sc]     = vA;
            *(short8*)&Vt[sr][sc + 8] = vB;
            __syncthreads();              // tile staged

            if (kt + 1 < nkt) {           // prefetch next tile (latency hidden)
                kA = *(const short8*)(kpb + (size_t)(kt + 1) * 64 * 512);
                kB = *(const short8*)(kpb + (size_t)(kt + 1) * 64 * 512 + 8);
                vA = *(const short8*)(vpb + (kt + 1) * 64);
                vB = *(const short8*)(vpb + (kt + 1) * 64 + 8);
            }

            const int k0 = kt * 64;
            float4v c[4];
#pragma unroll
            for (int j = 0; j < 4; j++) {
                short8 blo = *(const short8*)&Ks[j * 16 + col][rowg * 8];
                short8 bhi = *(const short8*)&Ks[j * 16 + col][32 + rowg * 8];
                float4v cc = (float4v){0.f, 0.f, 0.f, 0.f};
                cc = __builtin_amdgcn_mfma_f32_16x16x32_bf16(aq0, blo, cc, 0, 0, 0);
                cc = __builtin_amdgcn_mfma_f32_16x16x32_bf16(aq1, bhi, cc, 0, 0, 0);
                c[j] = cc;
            }

            if (kt == qt) {               // diagonal tile masks
#pragma unroll
                for (int j = 0; j < 4; j++) {
                    int pk = positions[k0 + j * 16 + col];
#pragma unroll
                    for (int r = 0; r < 4; r++)
                        if (pq[r] < pk) c[j][r] = -1e30f;
                }
            }

#pragma unroll
            for (int j = 0; j < 4; j++)
#pragma unroll
                for (int r = 0; r < 4; r++) {
                    float p = fast_exp2(c[j][r] - BIAS);
                    l_i[r] += p;
                    Ps[wave * 16 + rowg * 4 + r][j * 16 + col] = f2bf(p);
                }

            __asm__ volatile("s_waitcnt lgkmcnt(0)" ::: "memory");  // Ps wave-private

            short8 ap0 = *(const short8*)&Ps[wave * 16 + col][rowg * 8];
            short8 ap1 = *(const short8*)&Ps[wave * 16 + col][32 + rowg * 8];
#pragma unroll
            for (int n = 0; n < 4; n++) {
                short8 blo = *(const short8*)&Vt[n * 16 + col][rowg * 8];
                short8 bhi = *(const short8*)&Vt[n * 16 + col][32 + rowg * 8];
                float4v a2 = oacc[n];
                a2 = __builtin_amdgcn_mfma_f32_16x16x32_bf16(ap0, blo, a2, 0, 0, 0);
                a2 = __builtin_amdgcn_mfma_f32_16x16x32_bf16(ap1, bhi, a2, 0, 0, 0);
                oacc[n] = a2;
            }
        }

#pragma unroll
        for (int r = 0; r < 4; r++) {
#pragma unroll
            for (int off = 1; off < 16; off <<= 1)
                l_i[r] += __shfl_xor(l_i[r], off, 64);
            l_i[r] = 1.f / l_i[r];
        }
#pragma unroll
        for (int n = 0; n < 4; n++)
#pragma unroll
            for (int r = 0; r < 4; r++)
                ob[(size_t)(m0 + rowg * 4 + r) * HID + head * HD + n * 16 + col] =
                    f2bf(oacc[n][r] * l_i[r]);
    }
}

// ---------------------------------------------------------------------------
extern "C" void kernel_launch(void* const* d_in, const int* in_sizes, int n_in,
                              void* d_out, int out_size, void* d_ws, size_t ws_size,
                              hipStream_t stream)
{
    (void)in_sizes; (void)n_in; (void)out_size; (void)ws_size;

    const float* hidden    = (const float*)d_in[0];
    const int*   positions = (const int*)  d_in[1];
    const int*   sort_idx  = (const int*)  d_in[2];
    const float* q_proj_w  = (const float*)d_in[3];
    const float* o_proj_w  = (const float*)d_in[4];
    const float* k_w       = (const float*)d_in[5];
    const float* v_w       = (const float*)d_in[6];
    const float* q_norm_w  = (const float*)d_in[7];
    const float* k_norm_w  = (const float*)d_in[8];
    float* out = (float*)d_out;

    const size_t M1 = 1024 * 1024;
    short* Wqo = (short*)d_ws;           // 32 MB: q weights, then o weights
    short* Wkv = Wqo + 16 * M1;          // 4 MB
    short* Xbf = Wkv + 2 * M1;           // 8 MB (aliased as obf later)
    short* qb  = Xbf + 4 * M1;           // 8 MB
    short* kb  = qb  + 4 * M1;           // 2 MB (k only, stride 512)
    short* vt  = kb  + 1 * M1;           // 2 MB (v transposed [d][token])
    short* obf = Xbf;

    prep1<<<6656, 256, 0, stream>>>(hidden, q_proj_w, k_w, v_w, Xbf, Wqo, Wkv);

    gemm_qkv<<<384, 256, 0, stream>>>(Xbf, Wqo, Wkv, sort_idx, qb, kb, vt,
                                      positions, q_norm_w, k_norm_w);

    attn_plus<<<4608, 256, 0, stream>>>(qb, kb, vt, positions, obf,
                                        o_proj_w, Wqo);

    gemm_o<<<dim3(16, 16), 256, 0, stream>>>(obf, Wqo, sort_idx, out);
}